// Round 1
// baseline (950.468 us; speedup 1.0000x reference)
//
#include <hip/hip_runtime.h>

#define NPTS 20000
#define RS 68          // padded row stride for 32x64 tiles (breaks pow-2 bank strides)
#define EPSF 1e-5f

// ---------------- Kernel A: fused per-point attention ----------------
// LDS plan (~55.3 KB -> 2 blocks/CU):
struct __align__(16) SmemA {
  float slot[64 * 64];     // time-multiplexed weight matrix (Wq/Wl2/Wv/Wk/Ww1/Ww2)
  float B0[32 * RS];       // h1 -> V
  float B1[32 * RS];       // fc -> w
  float B2[32 * RS];       // pe -> w1
  float B3[32 * RS];       // rel
  float wl1[3 * 64];
  float bl1v[64], bl2v[64], bqv[64], bkv[64], bvv[64], bw1v[64], bw2v[64], gav[64], bav[64];
  float qv[64];
  float fn[64];            // feats[n]
  float cn[4];             // coords[n]
  float diffs[32 * 3];
  float tau[64];
  float part[256];
  int   idxs[32];
};

__device__ __forceinline__ void stageW(float* __restrict__ dst,
                                       const float* __restrict__ src, int t) {
  float4* d4 = (float4*)dst;
  const float4* s4 = (const float4*)src;
#pragma unroll
  for (int i = 0; i < 4; ++i) d4[i * 256 + t] = s4[i * 256 + t];
}

// acc[4][4] = A[k0:k0+4, :] @ W[:, d0:d0+4]; A stride RS (LDS), W 64x64 row-major (LDS)
__device__ __forceinline__ void mm_core(const float* __restrict__ A,
                                        const float* __restrict__ W,
                                        int k0, int d0, float acc[4][4]) {
#pragma unroll
  for (int a = 0; a < 4; ++a)
#pragma unroll
    for (int b = 0; b < 4; ++b) acc[a][b] = 0.f;
#pragma unroll
  for (int j0 = 0; j0 < 64; j0 += 4) {
    float4 av[4];
#pragma unroll
    for (int kk = 0; kk < 4; ++kk)
      av[kk] = *(const float4*)(A + (k0 + kk) * RS + j0);
#pragma unroll
    for (int jj = 0; jj < 4; ++jj) {
      float4 w = *(const float4*)(W + (j0 + jj) * 64 + d0);
#pragma unroll
      for (int kk = 0; kk < 4; ++kk) {
        float a = (&av[kk].x)[jj];
        acc[kk][0] += a * w.x; acc[kk][1] += a * w.y;
        acc[kk][2] += a * w.z; acc[kk][3] += a * w.w;
      }
    }
  }
}

__global__ __launch_bounds__(256) void attn_kernel(
    const float* __restrict__ coords, const float* __restrict__ feats,
    const float* __restrict__ Wq, const float* __restrict__ bq,
    const float* __restrict__ Wk, const float* __restrict__ bk,
    const float* __restrict__ Wv, const float* __restrict__ bv,
    const float* __restrict__ Wl1, const float* __restrict__ bl1,
    const float* __restrict__ Wl2, const float* __restrict__ bl2,
    const float* __restrict__ Ww1, const float* __restrict__ bw1,
    const float* __restrict__ Ww2, const float* __restrict__ bw2,
    const float* __restrict__ g_att, const float* __restrict__ b_att,
    const int* __restrict__ knn, float* __restrict__ h_out)
{
  __shared__ SmemA s;
  const int n = blockIdx.x;
  const int t = threadIdx.x;

  // -------- per-block staging of small constants --------
  if (t < 192) s.wl1[t] = Wl1[t];
  if (t < 64) {
    s.bl1v[t] = bl1[t]; s.bl2v[t] = bl2[t]; s.bqv[t] = bq[t];
    s.bkv[t] = bk[t];   s.bvv[t] = bv[t];   s.bw1v[t] = bw1[t];
    s.bw2v[t] = bw2[t]; s.gav[t] = g_att[t]; s.bav[t] = b_att[t];
    s.fn[t] = feats[(size_t)n * 64 + t];
  }
  if (t < 32) s.idxs[t] = knn[n * 33 + t];   // attention uses columns 0..31
  if (t < 3)  s.cn[t] = coords[(size_t)n * 3 + t];
  __syncthreads();                                        // S1

  if (t < 96) {
    int k = t / 3, c = t % 3;
    s.diffs[t] = coords[(size_t)s.idxs[k] * 3 + c] - s.cn[c];
  }
  stageW(s.slot, Wq, t);
  __syncthreads();                                        // S2: diffs + Wq visible

  // Q[d] = relu(feats_n . Wq[:,d] + bq[d])
  if (t < 64) {
    float q = s.bqv[t];
    for (int j = 0; j < 64; ++j) q += s.fn[j] * s.slot[j * 64 + t];
    s.qv[t] = fmaxf(q, 0.f);
  }
  // h1 = relu(diff @ Wl1 + bl1) -> B0  (2k x 4d mapping, all 256 threads)
  {
    int td = t & 15, tk = t >> 4, d0 = td * 4;
#pragma unroll
    for (int kk = 0; kk < 2; ++kk) {
      int k = tk * 2 + kk;
      float ax = 0.f, ay = 0.f, az = 0.f, aw = 0.f;
#pragma unroll
      for (int c = 0; c < 3; ++c) {
        float a = s.diffs[k * 3 + c];
        float4 w = *(const float4*)(s.wl1 + c * 64 + d0);
        ax += a * w.x; ay += a * w.y; az += a * w.z; aw += a * w.w;
      }
      float4 b = *(const float4*)(s.bl1v + d0);
      float4 o;
      o.x = fmaxf(ax + b.x, 0.f); o.y = fmaxf(ay + b.y, 0.f);
      o.z = fmaxf(az + b.z, 0.f); o.w = fmaxf(aw + b.w, 0.f);
      *(float4*)(s.B0 + k * RS + d0) = o;
    }
  }
  __syncthreads();                                        // S3: qv, B0 done; slot free

  stageW(s.slot, Wl2, t);
  __syncthreads();                                        // S4
  // fc = h1 @ Wl2 + bl2 -> B1   (4k x 4d mapping, threads 0..127)
  if (t < 128) {
    int td = t & 15, tk = t >> 4, d0 = td * 4, k0 = tk * 4;
    float acc[4][4];
    mm_core(s.B0, s.slot, k0, d0, acc);
    float4 b = *(const float4*)(s.bl2v + d0);
#pragma unroll
    for (int kk = 0; kk < 4; ++kk) {
      float4 o;
      o.x = acc[kk][0] + b.x; o.y = acc[kk][1] + b.y;
      o.z = acc[kk][2] + b.z; o.w = acc[kk][3] + b.w;
      *(float4*)(s.B1 + (k0 + kk) * RS + d0) = o;
    }
  }
  __syncthreads();                                        // S5: fc ready, slot free

  // pe = fc + feats[idx]  -> B2   (all 256 threads), then stage Wv
  {
    int td = t & 15, tk = t >> 4, d0 = td * 4;
#pragma unroll
    for (int i = 0; i < 2; ++i) {
      int k = tk + 16 * i;
      float4 f = *(const float4*)(feats + (size_t)s.idxs[k] * 64 + d0);
      float4 c = *(const float4*)(s.B1 + k * RS + d0);
      float4 o; o.x = c.x + f.x; o.y = c.y + f.y; o.z = c.z + f.z; o.w = c.w + f.w;
      *(float4*)(s.B2 + k * RS + d0) = o;
    }
  }
  stageW(s.slot, Wv, t);
  __syncthreads();                                        // S6
  // V = pe @ Wv + bv -> B0
  if (t < 128) {
    int td = t & 15, tk = t >> 4, d0 = td * 4, k0 = tk * 4;
    float acc[4][4];
    mm_core(s.B2, s.slot, k0, d0, acc);
    float4 b = *(const float4*)(s.bvv + d0);
#pragma unroll
    for (int kk = 0; kk < 4; ++kk) {
      float4 o;
      o.x = acc[kk][0] + b.x; o.y = acc[kk][1] + b.y;
      o.z = acc[kk][2] + b.z; o.w = acc[kk][3] + b.w;
      *(float4*)(s.B0 + (k0 + kk) * RS + d0) = o;
    }
  }
  __syncthreads();                                        // S7

  stageW(s.slot, Wk, t);
  __syncthreads();                                        // S8
  // rel = (relu(pe @ Wk + bk) - Q) * fc -> B3
  if (t < 128) {
    int td = t & 15, tk = t >> 4, d0 = td * 4, k0 = tk * 4;
    float acc[4][4];
    mm_core(s.B2, s.slot, k0, d0, acc);
    float4 b = *(const float4*)(s.bkv + d0);
    float4 q = *(const float4*)(s.qv + d0);
#pragma unroll
    for (int kk = 0; kk < 4; ++kk) {
      float4 fc = *(const float4*)(s.B1 + (k0 + kk) * RS + d0);
      float4 o;
      o.x = (fmaxf(acc[kk][0] + b.x, 0.f) - q.x) * fc.x;
      o.y = (fmaxf(acc[kk][1] + b.y, 0.f) - q.y) * fc.y;
      o.z = (fmaxf(acc[kk][2] + b.z, 0.f) - q.z) * fc.z;
      o.w = (fmaxf(acc[kk][3] + b.w, 0.f) - q.w) * fc.w;
      *(float4*)(s.B3 + (k0 + kk) * RS + d0) = o;
    }
  }
  __syncthreads();                                        // S9

  stageW(s.slot, Ww1, t);
  __syncthreads();                                        // S10
  // w1 = relu(rel @ Ww1 + bw1) -> B2 (pe dead)
  if (t < 128) {
    int td = t & 15, tk = t >> 4, d0 = td * 4, k0 = tk * 4;
    float acc[4][4];
    mm_core(s.B3, s.slot, k0, d0, acc);
    float4 b = *(const float4*)(s.bw1v + d0);
#pragma unroll
    for (int kk = 0; kk < 4; ++kk) {
      float4 o;
      o.x = fmaxf(acc[kk][0] + b.x, 0.f); o.y = fmaxf(acc[kk][1] + b.y, 0.f);
      o.z = fmaxf(acc[kk][2] + b.z, 0.f); o.w = fmaxf(acc[kk][3] + b.w, 0.f);
      *(float4*)(s.B2 + (k0 + kk) * RS + d0) = o;
    }
  }
  __syncthreads();                                        // S11

  stageW(s.slot, Ww2, t);
  __syncthreads();                                        // S12
  // w = w1 @ Ww2 + bw2 -> B1 (fc dead)
  if (t < 128) {
    int td = t & 15, tk = t >> 4, d0 = td * 4, k0 = tk * 4;
    float acc[4][4];
    mm_core(s.B2, s.slot, k0, d0, acc);
    float4 b = *(const float4*)(s.bw2v + d0);
#pragma unroll
    for (int kk = 0; kk < 4; ++kk) {
      float4 o;
      o.x = acc[kk][0] + b.x; o.y = acc[kk][1] + b.y;
      o.z = acc[kk][2] + b.z; o.w = acc[kk][3] + b.w;
      *(float4*)(s.B1 + (k0 + kk) * RS + d0) = o;
    }
  }
  __syncthreads();                                        // S13

  // -------- sparsemax over k per d (thread t<64 = column d) --------
  if (t < 64) {
    float a[32];
#pragma unroll
    for (int k = 0; k < 32; ++k) a[k] = s.B1[k * RS + t];
    // bitonic sort, descending, fully unrolled (branch-free)
#pragma unroll
    for (int size = 2; size <= 32; size <<= 1) {
#pragma unroll
      for (int stride = size >> 1; stride > 0; stride >>= 1) {
#pragma unroll
        for (int i = 0; i < 32; ++i) {
          int j = i ^ stride;
          if (j > i) {
            float x = a[i], y = a[j];
            float lo = fminf(x, y), hi = fmaxf(x, y);
            bool up = ((i & size) == 0);     // descending in "up" subsequences
            a[i] = up ? hi : lo;
            a[j] = up ? lo : hi;
          }
        }
      }
    }
    float csum = 0.f, csel = 0.f;
    int ksup = 1;
#pragma unroll
    for (int i = 0; i < 32; ++i) {
      csum += a[i];
      if (1.0f + (float)(i + 1) * a[i] > csum) { ksup = i + 1; csel = csum; }
    }
    s.tau[t] = (csel - 1.0f) / (float)ksup;
  }
  __syncthreads();                                        // S14

  // attn partials: p = max(w - tau, 0) * V, 4 k-groups of 8
  {
    int g = t >> 6, d = t & 63;
    float p = 0.f;
#pragma unroll
    for (int kk = 0; kk < 8; ++kk) {
      int k = g * 8 + kk;
      p += fmaxf(s.B1[k * RS + d] - s.tau[d], 0.f) * s.B0[k * RS + d];
    }
    s.part[g * 64 + d] = p;
  }
  __syncthreads();                                        // S15

  // x_att = 2*feats + attn; layernorm -> h (wave 0 only)
  if (t < 64) {
    float attn = s.part[t] + s.part[64 + t] + s.part[128 + t] + s.part[192 + t];
    float x = 2.f * s.fn[t] + attn;
    float sum = x, sum2 = x * x;
#pragma unroll
    for (int m = 1; m < 64; m <<= 1) {
      sum += __shfl_xor(sum, m, 64);
      sum2 += __shfl_xor(sum2, m, 64);
    }
    float mean = sum * (1.f / 64.f);
    float var = sum2 * (1.f / 64.f) - mean * mean;
    float inv = rsqrtf(var + EPSF);
    h_out[(size_t)n * 64 + t] = s.gav[t] * (x - mean) * inv + s.bav[t];
  }
}

// ---------------- Kernel B: graph conv + FFN + LN ----------------
// block = 4 waves, one point per wave, no __syncthreads needed.
__global__ __launch_bounds__(256) void gconv_kernel(
    const float* __restrict__ coords, const float* __restrict__ h,
    const float* __restrict__ Wsg, const float* __restrict__ bsg,
    const float* __restrict__ Wf, const float* __restrict__ bf,
    const float* __restrict__ g_ff, const float* __restrict__ b_ff,
    const int* __restrict__ knn, float* __restrict__ out)
{
  const int wave = threadIdx.x >> 6, lane = threadIdx.x & 63;
  const int p = blockIdx.x * 4 + wave;
  if (p >= NPTS) return;

  const int* row = knn + p * 33;      // graph uses columns 1..32 + self loop
  float hself = h[(size_t)p * 64 + lane];
  float aggH = hself;
  for (int k = 1; k <= 32; ++k) aggH += h[(size_t)row[k] * 64 + lane];

  // coords aggregate: lanes 0..32 each load one row's xyz, butterfly-sum
  float cx = 0.f, cy = 0.f, cz = 0.f;
  if (lane <= 32) {
    int src = (lane == 0) ? p : row[lane];
    cx = coords[(size_t)src * 3 + 0];
    cy = coords[(size_t)src * 3 + 1];
    cz = coords[(size_t)src * 3 + 2];
  }
#pragma unroll
  for (int m = 1; m < 64; m <<= 1) {
    cx += __shfl_xor(cx, m, 64);
    cy += __shfl_xor(cy, m, 64);
    cz += __shfl_xor(cz, m, 64);
  }
  const float inv33 = 1.0f / 33.0f;
  aggH *= inv33; cx *= inv33; cy *= inv33; cz *= inv33;

  // t1 = relu(agg @ Wsg + bsg); agg = [aggH(64) | cx cy cz]
  float t1 = bsg[lane];
  for (int c = 0; c < 64; ++c)
    t1 += __shfl(aggH, c, 64) * Wsg[c * 64 + lane];
  t1 += cx * Wsg[64 * 64 + lane] + cy * Wsg[65 * 64 + lane] + cz * Wsg[66 * 64 + lane];
  t1 = fmaxf(t1, 0.f);

  // t2 = t1 @ Wf + bf
  float t2 = bf[lane];
  for (int c = 0; c < 64; ++c)
    t2 += __shfl(t1, c, 64) * Wf[c * 64 + lane];

  float x = t2 + hself;
  float sum = x, sum2 = x * x;
#pragma unroll
  for (int m = 1; m < 64; m <<= 1) {
    sum += __shfl_xor(sum, m, 64);
    sum2 += __shfl_xor(sum2, m, 64);
  }
  float mean = sum * (1.f / 64.f);
  float var = sum2 * (1.f / 64.f) - mean * mean;
  out[(size_t)p * 64 + lane] = g_ff[lane] * (x - mean) * rsqrtf(var + EPSF) + b_ff[lane];
}

extern "C" void kernel_launch(void* const* d_in, const int* in_sizes, int n_in,
                              void* d_out, int out_size, void* d_ws, size_t ws_size,
                              hipStream_t stream) {
  (void)in_sizes; (void)n_in; (void)out_size; (void)ws_size;
  const float* coords = (const float*)d_in[0];
  const float* feats  = (const float*)d_in[1];
  const float* Wq  = (const float*)d_in[2];  const float* bq  = (const float*)d_in[3];
  const float* Wk  = (const float*)d_in[4];  const float* bk  = (const float*)d_in[5];
  const float* Wv  = (const float*)d_in[6];  const float* bv  = (const float*)d_in[7];
  const float* Wl1 = (const float*)d_in[8];  const float* bl1 = (const float*)d_in[9];
  const float* Wl2 = (const float*)d_in[10]; const float* bl2 = (const float*)d_in[11];
  const float* Ww1 = (const float*)d_in[12]; const float* bw1 = (const float*)d_in[13];
  const float* Ww2 = (const float*)d_in[14]; const float* bw2 = (const float*)d_in[15];
  const float* g_att = (const float*)d_in[16]; const float* b_att = (const float*)d_in[17];
  const float* Wsg = (const float*)d_in[18]; const float* bsg = (const float*)d_in[19];
  const float* Wf  = (const float*)d_in[20]; const float* bf  = (const float*)d_in[21];
  const float* g_ff = (const float*)d_in[22]; const float* b_ff = (const float*)d_in[23];
  const int* knn = (const int*)d_in[24];

  float* h   = (float*)d_ws;        // N*64 fp32 = 5.12 MB scratch
  float* out = (float*)d_out;

  attn_kernel<<<dim3(NPTS), dim3(256), 0, stream>>>(
      coords, feats, Wq, bq, Wk, bk, Wv, bv, Wl1, bl1, Wl2, bl2,
      Ww1, bw1, Ww2, bw2, g_att, b_att, knn, h);
  gconv_kernel<<<dim3((NPTS + 3) / 4), dim3(256), 0, stream>>>(
      coords, h, Wsg, bsg, Wf, bf, g_ff, b_ff, knn, out);
}

// Round 2
// 277.035 us; speedup vs baseline: 3.4309x; 3.4309x over previous
//
#include <hip/hip_runtime.h>

#define NPTS 20000
#define EPSF 1e-5f

typedef _Float16 half8 __attribute__((ext_vector_type(8)));
typedef float floatx4 __attribute__((ext_vector_type(4)));

// ---------------------------------------------------------------------------
// Weight prep: W (64x64 fp32, row-major, rows = K-dim) -> fp16, stored per
// column with XOR-swizzled 8-half chunks so B-fragment reads are single b128:
//   element [k][d] at  d*64 + (((k>>3) ^ (d&7)) << 3) + (k&7)
// ---------------------------------------------------------------------------
__global__ void prep_weights(const float* __restrict__ W0, const float* __restrict__ W1,
                             const float* __restrict__ W2, const float* __restrict__ W3,
                             const float* __restrict__ W4, _Float16* __restrict__ wtg) {
  const float* srcs[5] = {W0, W1, W2, W3, W4};
  int t = threadIdx.x;
  for (int mi = 0; mi < 5; ++mi) {
    const float* src = srcs[mi];
    _Float16* dst = wtg + mi * 4096;
    for (int i = 0; i < 16; ++i) {
      int lin = i * 256 + t;          // = k*64 + d
      int k = lin >> 6, d = lin & 63;
      dst[d * 64 + (((k >> 3) ^ (d & 7)) << 3) + (k & 7)] = (_Float16)src[lin];
    }
  }
}

// B-fragment load: cols tile nt, K-step ks. frag[j] = W[32ks+8g+j][16nt+c15]
__device__ __forceinline__ half8 ldWt(const _Float16* __restrict__ w,
                                      int c15, int g, int nt, int ks) {
  int c = nt * 16 + c15;
  int kg = ks * 4 + g;
  return *(const half8*)(w + c * 64 + ((kg ^ (c & 7)) << 3));
}

// ---------------------------------------------------------------------------
// Per-wave transpose buffer T: 64 cols x 32 rows fp32, XOR-swizzled 4-dword
// chunks: element [col][row] at col*32 + (((row>>2) ^ (col&7))<<2) + (row&3)
// ---------------------------------------------------------------------------
__device__ __forceinline__ void stC(float* __restrict__ Tw, int c15, int g,
                                    int mt, int nt, floatx4 v) {
  int col = nt * 16 + c15;
  int chunk = mt * 4 + g;                       // rows 16mt+4g .. +3
  int off = col * 32 + (((chunk ^ (col & 7))) << 2);
  *(floatx4*)(Tw + off) = v;                    // 16B aligned
}

// A-fragment: frag[j] = X[16mt+c15][32ks+8g+j], converted to fp16
__device__ __forceinline__ half8 ldA(const float* __restrict__ Tw,
                                     int c15, int g, int mt, int ks) {
  int m = mt * 16 + c15;
  half8 r;
#pragma unroll
  for (int j = 0; j < 8; ++j) {
    int c = ks * 32 + g * 8 + j;                // c&7 == j
    float v = Tw[c * 32 + ((((m >> 2) ^ j)) << 2) + (m & 3)];
    r[j] = (_Float16)v;
  }
  return r;
}

__device__ __forceinline__ void ldAfrags(const float* __restrict__ Tw,
                                         int c15, int g, half8 a[2][2]) {
#pragma unroll
  for (int mt = 0; mt < 2; ++mt)
#pragma unroll
    for (int ks = 0; ks < 2; ++ks) a[mt][ks] = ldA(Tw, c15, g, mt, ks);
}

__device__ __forceinline__ void domm(const _Float16* __restrict__ w,
                                     const half8 a[2][2], int c15, int g,
                                     floatx4 acc[2][4]) {
#pragma unroll
  for (int ks = 0; ks < 2; ++ks)
#pragma unroll
    for (int nt = 0; nt < 4; ++nt) {
      half8 b = ldWt(w, c15, g, nt, ks);
#pragma unroll
      for (int mt = 0; mt < 2; ++mt)
        acc[mt][nt] = __builtin_amdgcn_mfma_f32_16x16x32_f16(a[mt][ks], b, acc[mt][nt], 0, 0, 0);
    }
}

__device__ __forceinline__ void ld4(const float* __restrict__ p, int c15, float o[4]) {
#pragma unroll
  for (int nt = 0; nt < 4; ++nt) o[nt] = p[nt * 16 + c15];
}

__device__ __forceinline__ float readlane_f(float v, int l) {
  return __int_as_float(__builtin_amdgcn_readlane(__float_as_int(v), l));
}

// ---------------------------------------------------------------------------
// Kernel A: fused per-point attention; one wave per point, MFMA matmuls.
// ---------------------------------------------------------------------------
__global__ __launch_bounds__(256, 2) void attn_kernel(
    const float* __restrict__ coords, const float* __restrict__ feats,
    const float* __restrict__ Wq, const float* __restrict__ bq,
    const float* __restrict__ bk, const float* __restrict__ bv,
    const float* __restrict__ Wl1, const float* __restrict__ bl1,
    const float* __restrict__ bl2, const float* __restrict__ bw1,
    const float* __restrict__ bw2, const float* __restrict__ g_att,
    const float* __restrict__ b_att, const int* __restrict__ knn,
    const _Float16* __restrict__ wtg, _Float16* __restrict__ h_out)
{
  __shared__ float Tsh[4][2048];
  const int wv = threadIdx.x >> 6, lane = threadIdx.x & 63;
  const int c15 = lane & 15, g = lane >> 4;
  const int n = blockIdx.x * 4 + wv;
  float* Tw = Tsh[wv];
  const int* row = knn + (size_t)n * 33;

  const _Float16* wt_l2 = wtg;
  const _Float16* wt_v  = wtg + 4096;
  const _Float16* wt_k  = wtg + 8192;
  const _Float16* wt_w1 = wtg + 12288;
  const _Float16* wt_w2 = wtg + 16384;

  // ---- biases at this lane's 4 columns ----
  float bl2v[4], bvv[4], bkv[4], bw1v[4], bw2v[4];
  ld4(bl2, c15, bl2v); ld4(bv, c15, bvv); ld4(bk, c15, bkv);
  ld4(bw1, c15, bw1v); ld4(bw2, c15, bw2v);

  // ---- Q[lane] = relu(feats[n] . Wq[:,lane] + bq[lane]) ----
  float fv = feats[(size_t)n * 64 + lane];
  float qacc = bq[lane];
#pragma unroll 16
  for (int j = 0; j < 64; ++j)
    qacc += readlane_f(fv, j) * Wq[j * 64 + lane];
  qacc = fmaxf(qacc, 0.f);
  float q4[4];
#pragma unroll
  for (int nt = 0; nt < 4; ++nt) q4[nt] = __shfl(qacc, nt * 16 + c15, 64);

  // ---- h1 = relu(diff @ Wl1 + bl1), built directly in A-layout ----
  half8 aH[2][2];
  {
    float cnx = coords[(size_t)n * 3], cny = coords[(size_t)n * 3 + 1], cnz = coords[(size_t)n * 3 + 2];
#pragma unroll
    for (int mt = 0; mt < 2; ++mt) {
      int id = row[mt * 16 + c15];
      float dx = coords[(size_t)id * 3] - cnx;
      float dy = coords[(size_t)id * 3 + 1] - cny;
      float dz = coords[(size_t)id * 3 + 2] - cnz;
#pragma unroll
      for (int ks = 0; ks < 2; ++ks)
#pragma unroll
        for (int j = 0; j < 8; ++j) {
          int c = ks * 32 + g * 8 + j;
          float v = dx * Wl1[c] + dy * Wl1[64 + c] + dz * Wl1[128 + c] + bl1[c];
          aH[mt][ks][j] = (_Float16)fmaxf(v, 0.f);
        }
    }
  }

  // ---- fc = h1 @ Wl2 + bl2 (C-layout regs) ----
  floatx4 fc[2][4] = {};
  domm(wt_l2, aH, c15, g, fc);
#pragma unroll
  for (int mt = 0; mt < 2; ++mt)
#pragma unroll
    for (int nt = 0; nt < 4; ++nt) fc[mt][nt] += bl2v[nt];

  // ---- pe = fc + feats[idx]; store to T; reload as A-frags ----
#pragma unroll
  for (int mt = 0; mt < 2; ++mt) {
    int idr[4];
#pragma unroll
    for (int r = 0; r < 4; ++r) idr[r] = row[mt * 16 + g * 4 + r];
#pragma unroll
    for (int nt = 0; nt < 4; ++nt) {
      floatx4 pe;
#pragma unroll
      for (int r = 0; r < 4; ++r)
        pe[r] = fc[mt][nt][r] + feats[(size_t)idr[r] * 64 + nt * 16 + c15];
      stC(Tw, c15, g, mt, nt, pe);
    }
  }
  __builtin_amdgcn_wave_barrier();
  half8 aP[2][2];
  ldAfrags(Tw, c15, g, aP);

  // ---- V = pe @ Wv + bv (keep in regs) ----
  floatx4 V[2][4] = {};
  domm(wt_v, aP, c15, g, V);
#pragma unroll
  for (int mt = 0; mt < 2; ++mt)
#pragma unroll
    for (int nt = 0; nt < 4; ++nt) V[mt][nt] += bvv[nt];

  // ---- rel = (relu(pe @ Wk + bk) - Q) * fc -> T ----
  {
    floatx4 KR[2][4] = {};
    domm(wt_k, aP, c15, g, KR);
    __builtin_amdgcn_wave_barrier();
#pragma unroll
    for (int mt = 0; mt < 2; ++mt)
#pragma unroll
      for (int nt = 0; nt < 4; ++nt) {
        floatx4 v;
#pragma unroll
        for (int r = 0; r < 4; ++r)
          v[r] = (fmaxf(KR[mt][nt][r] + bkv[nt], 0.f) - q4[nt]) * fc[mt][nt][r];
        stC(Tw, c15, g, mt, nt, v);
      }
  }
  __builtin_amdgcn_wave_barrier();
  half8 aR[2][2];
  ldAfrags(Tw, c15, g, aR);

  // ---- w1 = relu(rel @ Ww1 + bw1) -> T ----
  {
    floatx4 W1[2][4] = {};
    domm(wt_w1, aR, c15, g, W1);
    __builtin_amdgcn_wave_barrier();
#pragma unroll
    for (int mt = 0; mt < 2; ++mt)
#pragma unroll
      for (int nt = 0; nt < 4; ++nt) {
        floatx4 v;
#pragma unroll
        for (int r = 0; r < 4; ++r) v[r] = fmaxf(W1[mt][nt][r] + bw1v[nt], 0.f);
        stC(Tw, c15, g, mt, nt, v);
      }
  }
  __builtin_amdgcn_wave_barrier();
  half8 aW[2][2];
  ldAfrags(Tw, c15, g, aW);

  // ---- w = w1 @ Ww2 + bw2 (regs + T for the column sort) ----
  floatx4 ww[2][4] = {};
  domm(wt_w2, aW, c15, g, ww);
  __builtin_amdgcn_wave_barrier();
#pragma unroll
  for (int mt = 0; mt < 2; ++mt)
#pragma unroll
    for (int nt = 0; nt < 4; ++nt) {
      ww[mt][nt] += bw2v[nt];
      stC(Tw, c15, g, mt, nt, ww[mt][nt]);
    }
  __builtin_amdgcn_wave_barrier();

  // ---- sparsemax over k: lane d = lane sorts column d ----
  float a[32];
#pragma unroll
  for (int i = 0; i < 8; ++i) {
    floatx4 ch = *(const floatx4*)(Tw + lane * 32 + ((i ^ (lane & 7)) << 2));
#pragma unroll
    for (int r = 0; r < 4; ++r) a[i * 4 + r] = ch[r];
  }
  // bitonic sort descending, branch-free
#pragma unroll
  for (int size = 2; size <= 32; size <<= 1) {
#pragma unroll
    for (int stride = size >> 1; stride > 0; stride >>= 1) {
#pragma unroll
      for (int i = 0; i < 32; ++i) {
        int j = i ^ stride;
        if (j > i) {
          float x = a[i], y = a[j];
          float lo = fminf(x, y), hi = fmaxf(x, y);
          bool up = ((i & size) == 0);
          a[i] = up ? hi : lo;
          a[j] = up ? lo : hi;
        }
      }
    }
  }
  float csum = 0.f, csel = 0.f;
  int ksup = 1;
#pragma unroll
  for (int i = 0; i < 32; ++i) {
    csum += a[i];
    if (1.0f + (float)(i + 1) * a[i] > csum) { ksup = i + 1; csel = csum; }
  }
  float tau = (csel - 1.0f) / (float)ksup;

  float t4[4];
#pragma unroll
  for (int nt = 0; nt < 4; ++nt) t4[nt] = __shfl(tau, nt * 16 + c15, 64);

  // ---- attn = sum_k max(w - tau, 0) * V ; x_att = 2*feats + attn ----
  float x4[4];
#pragma unroll
  for (int nt = 0; nt < 4; ++nt) {
    float ssum = 0.f;
#pragma unroll
    for (int mt = 0; mt < 2; ++mt)
#pragma unroll
      for (int r = 0; r < 4; ++r)
        ssum += fmaxf(ww[mt][nt][r] - t4[nt], 0.f) * V[mt][nt][r];
    ssum += __shfl_xor(ssum, 16, 64);
    ssum += __shfl_xor(ssum, 32, 64);
    x4[nt] = 2.f * __shfl(fv, nt * 16 + c15, 64) + ssum;
  }

  // ---- LayerNorm over d; store h (fp16) ----
  float sum = x4[0] + x4[1] + x4[2] + x4[3];
  float sum2 = x4[0] * x4[0] + x4[1] * x4[1] + x4[2] * x4[2] + x4[3] * x4[3];
#pragma unroll
  for (int m = 1; m < 16; m <<= 1) {
    sum += __shfl_xor(sum, m, 64);
    sum2 += __shfl_xor(sum2, m, 64);
  }
  float mean = sum * (1.f / 64.f);
  float var = sum2 * (1.f / 64.f) - mean * mean;
  float inv = rsqrtf(var + EPSF);
  float xv = x4[g];   // lane's written column = 16g + c15 = lane
  h_out[(size_t)n * 64 + lane] =
      (_Float16)(g_att[lane] * (xv - mean) * inv + b_att[lane]);
}

// ---------------------------------------------------------------------------
// Kernel B: graph conv + FFN + LN. One wave per point, h is fp16.
// ---------------------------------------------------------------------------
__global__ __launch_bounds__(256) void gconv_kernel(
    const float* __restrict__ coords, const _Float16* __restrict__ h,
    const float* __restrict__ Wsg, const float* __restrict__ bsg,
    const float* __restrict__ Wf, const float* __restrict__ bf,
    const float* __restrict__ g_ff, const float* __restrict__ b_ff,
    const int* __restrict__ knn, float* __restrict__ out)
{
  const int wave = threadIdx.x >> 6, lane = threadIdx.x & 63;
  const int p = blockIdx.x * 4 + wave;
  if (p >= NPTS) return;

  const int* row = knn + (size_t)p * 33;
  float hself = (float)h[(size_t)p * 64 + lane];
  float aggH = hself;
#pragma unroll 8
  for (int k = 1; k <= 32; ++k) aggH += (float)h[(size_t)row[k] * 64 + lane];

  float cx = 0.f, cy = 0.f, cz = 0.f;
  if (lane <= 32) {
    int src = (lane == 0) ? p : row[lane];
    cx = coords[(size_t)src * 3 + 0];
    cy = coords[(size_t)src * 3 + 1];
    cz = coords[(size_t)src * 3 + 2];
  }
#pragma unroll
  for (int m = 1; m < 64; m <<= 1) {
    cx += __shfl_xor(cx, m, 64);
    cy += __shfl_xor(cy, m, 64);
    cz += __shfl_xor(cz, m, 64);
  }
  const float inv33 = 1.0f / 33.0f;
  aggH *= inv33; cx *= inv33; cy *= inv33; cz *= inv33;

  float t1 = bsg[lane];
#pragma unroll 8
  for (int c = 0; c < 64; ++c)
    t1 += __shfl(aggH, c, 64) * Wsg[c * 64 + lane];
  t1 += cx * Wsg[64 * 64 + lane] + cy * Wsg[65 * 64 + lane] + cz * Wsg[66 * 64 + lane];
  t1 = fmaxf(t1, 0.f);

  float t2 = bf[lane];
#pragma unroll 8
  for (int c = 0; c < 64; ++c)
    t2 += __shfl(t1, c, 64) * Wf[c * 64 + lane];

  float x = t2 + hself;
  float sum = x, sum2 = x * x;
#pragma unroll
  for (int m = 1; m < 64; m <<= 1) {
    sum += __shfl_xor(sum, m, 64);
    sum2 += __shfl_xor(sum2, m, 64);
  }
  float mean = sum * (1.f / 64.f);
  float var = sum2 * (1.f / 64.f) - mean * mean;
  out[(size_t)p * 64 + lane] = g_ff[lane] * (x - mean) * rsqrtf(var + EPSF) + b_ff[lane];
}

extern "C" void kernel_launch(void* const* d_in, const int* in_sizes, int n_in,
                              void* d_out, int out_size, void* d_ws, size_t ws_size,
                              hipStream_t stream) {
  (void)in_sizes; (void)n_in; (void)out_size; (void)ws_size;
  const float* coords = (const float*)d_in[0];
  const float* feats  = (const float*)d_in[1];
  const float* Wq  = (const float*)d_in[2];  const float* bq  = (const float*)d_in[3];
  const float* Wk  = (const float*)d_in[4];  const float* bk  = (const float*)d_in[5];
  const float* Wv  = (const float*)d_in[6];  const float* bv  = (const float*)d_in[7];
  const float* Wl1 = (const float*)d_in[8];  const float* bl1 = (const float*)d_in[9];
  const float* Wl2 = (const float*)d_in[10]; const float* bl2 = (const float*)d_in[11];
  const float* Ww1 = (const float*)d_in[12]; const float* bw1 = (const float*)d_in[13];
  const float* Ww2 = (const float*)d_in[14]; const float* bw2 = (const float*)d_in[15];
  const float* g_att = (const float*)d_in[16]; const float* b_att = (const float*)d_in[17];
  const float* Wsg = (const float*)d_in[18]; const float* bsg = (const float*)d_in[19];
  const float* Wf  = (const float*)d_in[20]; const float* bf  = (const float*)d_in[21];
  const float* g_ff = (const float*)d_in[22]; const float* b_ff = (const float*)d_in[23];
  const int* knn = (const int*)d_in[24];

  // workspace: [0, 2.56MB) h (fp16), [2.5MiB, +40KB) swizzled fp16 weights
  _Float16* h   = (_Float16*)d_ws;
  _Float16* wtg = (_Float16*)((char*)d_ws + 2621440);
  float* out = (float*)d_out;

  prep_weights<<<dim3(1), dim3(256), 0, stream>>>(Wl2, Wv, Wk, Ww1, Ww2, wtg);
  attn_kernel<<<dim3(NPTS / 4), dim3(256), 0, stream>>>(
      coords, feats, Wq, bq, bk, bv, Wl1, bl1, bl2, bw1, bw2,
      g_att, b_att, knn, wtg, h);
  gconv_kernel<<<dim3((NPTS + 3) / 4), dim3(256), 0, stream>>>(
      coords, h, Wsg, bsg, Wf, bf, g_ff, b_ff, knn, out);
}

// Round 3
// 245.230 us; speedup vs baseline: 3.8758x; 1.1297x over previous
//
#include <hip/hip_runtime.h>

#define NPTS 20000
#define EPSF 1e-5f

typedef _Float16 half8 __attribute__((ext_vector_type(8)));
typedef float floatx4 __attribute__((ext_vector_type(4)));

// ---------------------------------------------------------------------------
// Weight prep: W (64x64 fp32 row-major, rows = K-dim) -> fp16, per column,
// XOR-swizzled 8-half chunks: [k][d] -> d*64 + (((k>>3)^(d&7))<<3) + (k&7)
// One block per matrix. Order: Wl2, Wv, Wk, Ww1, Ww2, Wq.
// ---------------------------------------------------------------------------
__global__ void prep_weights(const float* __restrict__ W0, const float* __restrict__ W1,
                             const float* __restrict__ W2, const float* __restrict__ W3,
                             const float* __restrict__ W4, const float* __restrict__ W5,
                             _Float16* __restrict__ wtg) {
  const float* srcs[6] = {W0, W1, W2, W3, W4, W5};
  const float* src = srcs[blockIdx.x];
  _Float16* dst = wtg + blockIdx.x * 4096;
  int t = threadIdx.x;
#pragma unroll
  for (int i = 0; i < 16; ++i) {
    int lin = i * 256 + t;            // = k*64 + d
    int k = lin >> 6, d = lin & 63;
    dst[d * 64 + (((k >> 3) ^ (d & 7)) << 3) + (k & 7)] = (_Float16)src[lin];
  }
}

// B-fragment: frag[j] = W[32ks+8g+j][16nt+c15]
__device__ __forceinline__ half8 ldWt(const _Float16* __restrict__ w,
                                      int c15, int g, int nt, int ks) {
  int c = nt * 16 + c15;
  int kg = ks * 4 + g;
  return *(const half8*)(w + c * 64 + ((kg ^ (c & 7)) << 3));
}

// Per-wave transpose buffer T: 64 cols x 32 rows fp32, XOR-swizzled chunks:
// [col][row] -> col*32 + (((row>>2)^(col&7))<<2) + (row&3)
__device__ __forceinline__ void stC(float* __restrict__ Tw, int c15, int g,
                                    int mt, int nt, floatx4 v) {
  int col = nt * 16 + c15;
  int chunk = mt * 4 + g;
  *(floatx4*)(Tw + col * 32 + ((chunk ^ (col & 7)) << 2)) = v;
}

__device__ __forceinline__ floatx4 ldCread(const float* __restrict__ Tw,
                                           int c15, int g, int mt, int nt) {
  int col = nt * 16 + c15;
  int chunk = mt * 4 + g;
  return *(const floatx4*)(Tw + col * 32 + ((chunk ^ (col & 7)) << 2));
}

// A-fragment from T: frag[j] = X[16mt+c15][32ks+8g+j] (fp32 -> fp16)
__device__ __forceinline__ half8 ldA(const float* __restrict__ Tw,
                                     int c15, int g, int mt, int ks) {
  int m = mt * 16 + c15;
  half8 r;
#pragma unroll
  for (int j = 0; j < 8; ++j) {
    int c = ks * 32 + g * 8 + j;                // c&7 == j
    r[j] = (_Float16)Tw[c * 32 + (((m >> 2) ^ j) << 2) + (m & 3)];
  }
  return r;
}

__device__ __forceinline__ void ldAfrags(const float* __restrict__ Tw,
                                         int c15, int g, half8 a[2][2]) {
#pragma unroll
  for (int mt = 0; mt < 2; ++mt)
#pragma unroll
    for (int ks = 0; ks < 2; ++ks) a[mt][ks] = ldA(Tw, c15, g, mt, ks);
}

__device__ __forceinline__ void domm(const _Float16* __restrict__ w,
                                     const half8 a[2][2], int c15, int g,
                                     floatx4 acc[2][4]) {
#pragma unroll
  for (int ks = 0; ks < 2; ++ks)
#pragma unroll
    for (int nt = 0; nt < 4; ++nt) {
      half8 b = ldWt(w, c15, g, nt, ks);
#pragma unroll
      for (int mt = 0; mt < 2; ++mt)
        acc[mt][nt] = __builtin_amdgcn_mfma_f32_16x16x32_f16(a[mt][ks], b, acc[mt][nt], 0, 0, 0);
    }
}

// ---------------------------------------------------------------------------
// Q precompute: Q = relu(feats @ Wq + bq), 32 points per wave, fp16 out.
// ---------------------------------------------------------------------------
__global__ __launch_bounds__(256) void q_kernel(const float* __restrict__ feats,
                                                const float* __restrict__ bq,
                                                const _Float16* __restrict__ wtg,
                                                _Float16* __restrict__ Qh) {
  const int wv = threadIdx.x >> 6, lane = threadIdx.x & 63;
  const int c15 = lane & 15, g = lane >> 4;
  const int n0 = (blockIdx.x * 4 + wv) * 32;
  const _Float16* wq = wtg + 5 * 4096;

  half8 a[2][2];
#pragma unroll
  for (int mt = 0; mt < 2; ++mt) {
    int r = n0 + mt * 16 + c15;
    if (r > NPTS - 1) r = NPTS - 1;
#pragma unroll
    for (int ks = 0; ks < 2; ++ks) {
      const float* p = feats + (size_t)r * 64 + ks * 32 + g * 8;
      float4 u0 = *(const float4*)p, u1 = *(const float4*)(p + 4);
      a[mt][ks][0] = (_Float16)u0.x; a[mt][ks][1] = (_Float16)u0.y;
      a[mt][ks][2] = (_Float16)u0.z; a[mt][ks][3] = (_Float16)u0.w;
      a[mt][ks][4] = (_Float16)u1.x; a[mt][ks][5] = (_Float16)u1.y;
      a[mt][ks][6] = (_Float16)u1.z; a[mt][ks][7] = (_Float16)u1.w;
    }
  }
  floatx4 acc[2][4] = {};
  domm(wq, a, c15, g, acc);
#pragma unroll
  for (int nt = 0; nt < 4; ++nt) {
    float bqv = bq[nt * 16 + c15];
#pragma unroll
    for (int mt = 0; mt < 2; ++mt)
#pragma unroll
      for (int r = 0; r < 4; ++r) {
        int n = n0 + mt * 16 + g * 4 + r;
        if (n < NPTS)
          Qh[(size_t)n * 64 + nt * 16 + c15] = (_Float16)fmaxf(acc[mt][nt][r] + bqv, 0.f);
      }
  }
}

// ---------------------------------------------------------------------------
// Kernel A: fused per-point attention; one wave per point, MFMA matmuls.
// Dataflow ordered to minimize concurrent fp32 accumulators (reg pressure).
// ---------------------------------------------------------------------------
__global__ __launch_bounds__(256, 4) void attn_kernel(
    const float* __restrict__ coords, const float* __restrict__ feats,
    const float* __restrict__ bk, const float* __restrict__ bv,
    const float* __restrict__ Wl1, const float* __restrict__ bl1,
    const float* __restrict__ bl2, const float* __restrict__ bw1,
    const float* __restrict__ bw2, const float* __restrict__ g_att,
    const float* __restrict__ b_att, const int* __restrict__ knn,
    const _Float16* __restrict__ wtg, const _Float16* __restrict__ Qh,
    _Float16* __restrict__ h_out)
{
  __shared__ float Tsh[4][2048];
  const int wv = threadIdx.x >> 6, lane = threadIdx.x & 63;
  const int c15 = lane & 15, g = lane >> 4;
  const int n = blockIdx.x * 4 + wv;
  float* Tw = Tsh[wv];
  const int* row = knn + (size_t)n * 33;

  const _Float16* wt_l2 = wtg;
  const _Float16* wt_v  = wtg + 4096;
  const _Float16* wt_k  = wtg + 8192;
  const _Float16* wt_w1 = wtg + 12288;
  const _Float16* wt_w2 = wtg + 16384;

  // ---- h1 = relu(diff @ Wl1 + bl1), built directly in A-layout ----
  half8 aH[2][2];
  {
    float cnx = coords[(size_t)n * 3], cny = coords[(size_t)n * 3 + 1],
          cnz = coords[(size_t)n * 3 + 2];
#pragma unroll
    for (int ks = 0; ks < 2; ++ks) {
      int c0 = ks * 32 + g * 8;
      float4 wx0 = *(const float4*)(Wl1 + c0),       wx1 = *(const float4*)(Wl1 + c0 + 4);
      float4 wy0 = *(const float4*)(Wl1 + 64 + c0),  wy1 = *(const float4*)(Wl1 + 64 + c0 + 4);
      float4 wz0 = *(const float4*)(Wl1 + 128 + c0), wz1 = *(const float4*)(Wl1 + 128 + c0 + 4);
      float4 bb0 = *(const float4*)(bl1 + c0),       bb1 = *(const float4*)(bl1 + c0 + 4);
      float wx[8] = {wx0.x,wx0.y,wx0.z,wx0.w,wx1.x,wx1.y,wx1.z,wx1.w};
      float wy[8] = {wy0.x,wy0.y,wy0.z,wy0.w,wy1.x,wy1.y,wy1.z,wy1.w};
      float wz[8] = {wz0.x,wz0.y,wz0.z,wz0.w,wz1.x,wz1.y,wz1.z,wz1.w};
      float bb[8] = {bb0.x,bb0.y,bb0.z,bb0.w,bb1.x,bb1.y,bb1.z,bb1.w};
#pragma unroll
      for (int mt = 0; mt < 2; ++mt) {
        int id = row[mt * 16 + c15];
        float dx = coords[(size_t)id * 3] - cnx;
        float dy = coords[(size_t)id * 3 + 1] - cny;
        float dz = coords[(size_t)id * 3 + 2] - cnz;
#pragma unroll
        for (int j = 0; j < 8; ++j)
          aH[mt][ks][j] = (_Float16)fmaxf(dx * wx[j] + dy * wy[j] + dz * wz[j] + bb[j], 0.f);
      }
    }
  }

  // ---- fc = h1 @ Wl2 + bl2 ----
  floatx4 fc[2][4] = {};
  domm(wt_l2, aH, c15, g, fc);
#pragma unroll
  for (int nt = 0; nt < 4; ++nt) {
    float b = bl2[nt * 16 + c15];
#pragma unroll
    for (int mt = 0; mt < 2; ++mt) fc[mt][nt] += b;
  }

  // ---- pe = fc + feats[idx] -> T; aP frags ----
#pragma unroll
  for (int mt = 0; mt < 2; ++mt) {
    int idr[4];
#pragma unroll
    for (int r = 0; r < 4; ++r) idr[r] = row[mt * 16 + g * 4 + r];
#pragma unroll
    for (int nt = 0; nt < 4; ++nt) {
      floatx4 pe;
#pragma unroll
      for (int r = 0; r < 4; ++r)
        pe[r] = fc[mt][nt][r] + feats[(size_t)idr[r] * 64 + nt * 16 + c15];
      stC(Tw, c15, g, mt, nt, pe);
    }
  }
  __builtin_amdgcn_wave_barrier();
  half8 aP[2][2];
  ldAfrags(Tw, c15, g, aP);

  // ---- KR = pe @ Wk ; rel = (relu(KR+bk) - Q) * fc -> T ----
  {
    floatx4 KR[2][4] = {};
    domm(wt_k, aP, c15, g, KR);
    __builtin_amdgcn_wave_barrier();
#pragma unroll
    for (int nt = 0; nt < 4; ++nt) {
      float bkv = bk[nt * 16 + c15];
      float q4 = (float)Qh[(size_t)n * 64 + nt * 16 + c15];
#pragma unroll
      for (int mt = 0; mt < 2; ++mt) {
        floatx4 v;
#pragma unroll
        for (int r = 0; r < 4; ++r)
          v[r] = (fmaxf(KR[mt][nt][r] + bkv, 0.f) - q4) * fc[mt][nt][r];
        stC(Tw, c15, g, mt, nt, v);
      }
    }
  }
  __builtin_amdgcn_wave_barrier();
  half8 aR[2][2];
  ldAfrags(Tw, c15, g, aR);

  // ---- w1 = relu(rel @ Ww1 + bw1) -> T ----
  {
    floatx4 W1[2][4] = {};
    domm(wt_w1, aR, c15, g, W1);
    __builtin_amdgcn_wave_barrier();
#pragma unroll
    for (int nt = 0; nt < 4; ++nt) {
      float b = bw1[nt * 16 + c15];
#pragma unroll
      for (int mt = 0; mt < 2; ++mt) {
        floatx4 v;
#pragma unroll
        for (int r = 0; r < 4; ++r) v[r] = fmaxf(W1[mt][nt][r] + b, 0.f);
        stC(Tw, c15, g, mt, nt, v);
      }
    }
  }
  __builtin_amdgcn_wave_barrier();
  half8 aW[2][2];
  ldAfrags(Tw, c15, g, aW);

  // ---- w = w1 @ Ww2 + bw2 -> T (regs die; re-read later) ----
  {
    floatx4 WW[2][4] = {};
    domm(wt_w2, aW, c15, g, WW);
    __builtin_amdgcn_wave_barrier();
#pragma unroll
    for (int nt = 0; nt < 4; ++nt) {
      float b = bw2[nt * 16 + c15];
#pragma unroll
      for (int mt = 0; mt < 2; ++mt) stC(Tw, c15, g, mt, nt, WW[mt][nt] + b);
    }
  }
  __builtin_amdgcn_wave_barrier();

  // ---- V = pe @ Wv + bv (aP still live, cheap fp16 frags) ----
  floatx4 V[2][4] = {};
  domm(wt_v, aP, c15, g, V);
#pragma unroll
  for (int nt = 0; nt < 4; ++nt) {
    float b = bv[nt * 16 + c15];
#pragma unroll
    for (int mt = 0; mt < 2; ++mt) V[mt][nt] += b;
  }

  // ---- sparsemax: lane d = lane sorts column d (from T) ----
  float a[32];
#pragma unroll
  for (int i = 0; i < 8; ++i) {
    floatx4 ch = *(const floatx4*)(Tw + lane * 32 + ((i ^ (lane & 7)) << 2));
#pragma unroll
    for (int r = 0; r < 4; ++r) a[i * 4 + r] = ch[r];
  }
#pragma unroll
  for (int size = 2; size <= 32; size <<= 1) {
#pragma unroll
    for (int stride = size >> 1; stride > 0; stride >>= 1) {
#pragma unroll
      for (int i = 0; i < 32; ++i) {
        int j = i ^ stride;
        if (j > i) {
          float x = a[i], y = a[j];
          float lo = fminf(x, y), hi = fmaxf(x, y);
          bool up = ((i & size) == 0);
          a[i] = up ? hi : lo;
          a[j] = up ? lo : hi;
        }
      }
    }
  }
  float csum = 0.f, csel = 0.f;
  int ksup = 1;
#pragma unroll
  for (int i = 0; i < 32; ++i) {
    csum += a[i];
    if (1.0f + (float)(i + 1) * a[i] > csum) { ksup = i + 1; csel = csum; }
  }
  float tau = (csel - 1.0f) / (float)ksup;

  // ---- attn = sum_k max(w - tau, 0) * V ; x_att = 2*feats + attn; LN ----
  float x4[4];
#pragma unroll
  for (int nt = 0; nt < 4; ++nt) {
    float t4 = __shfl(tau, nt * 16 + c15, 64);
    float ssum = 0.f;
#pragma unroll
    for (int mt = 0; mt < 2; ++mt) {
      floatx4 w4 = ldCread(Tw, c15, g, mt, nt);
#pragma unroll
      for (int r = 0; r < 4; ++r)
        ssum += fmaxf(w4[r] - t4, 0.f) * V[mt][nt][r];
    }
    ssum += __shfl_xor(ssum, 16, 64);
    ssum += __shfl_xor(ssum, 32, 64);
    x4[nt] = 2.f * feats[(size_t)n * 64 + nt * 16 + c15] + ssum;
  }

  float sum = x4[0] + x4[1] + x4[2] + x4[3];
  float sum2 = x4[0] * x4[0] + x4[1] * x4[1] + x4[2] * x4[2] + x4[3] * x4[3];
#pragma unroll
  for (int m = 1; m < 16; m <<= 1) {
    sum += __shfl_xor(sum, m, 64);
    sum2 += __shfl_xor(sum2, m, 64);
  }
  float mean = sum * (1.f / 64.f);
  float var = sum2 * (1.f / 64.f) - mean * mean;
  float inv = rsqrtf(var + EPSF);
  h_out[(size_t)n * 64 + lane] =
      (_Float16)(g_att[lane] * (x4[g] - mean) * inv + b_att[lane]);
}

// ---------------------------------------------------------------------------
// Kernel B: graph conv + FFN + LN. Two points per wave (shared weight loads).
// ---------------------------------------------------------------------------
__global__ __launch_bounds__(256) void gconv_kernel(
    const float* __restrict__ coords, const _Float16* __restrict__ h,
    const float* __restrict__ Wsg, const float* __restrict__ bsg,
    const float* __restrict__ Wf, const float* __restrict__ bf,
    const float* __restrict__ g_ff, const float* __restrict__ b_ff,
    const int* __restrict__ knn, float* __restrict__ out)
{
  const int wave = threadIdx.x >> 6, lane = threadIdx.x & 63;
  const int p0 = (blockIdx.x * 4 + wave) * 2, p1 = p0 + 1;
  if (p0 >= NPTS) return;

  const int* rowA = knn + (size_t)p0 * 33;
  const int* rowB = knn + (size_t)p1 * 33;
  float hA = (float)h[(size_t)p0 * 64 + lane];
  float hB = (float)h[(size_t)p1 * 64 + lane];
  float aggA = hA, aggB = hB;
#pragma unroll 8
  for (int k = 1; k <= 32; ++k) {
    aggA += (float)h[(size_t)rowA[k] * 64 + lane];
    aggB += (float)h[(size_t)rowB[k] * 64 + lane];
  }

  float cxA = 0.f, cyA = 0.f, czA = 0.f, cxB = 0.f, cyB = 0.f, czB = 0.f;
  if (lane <= 32) {
    int sA = (lane == 0) ? p0 : rowA[lane];
    int sB = (lane == 0) ? p1 : rowB[lane];
    cxA = coords[(size_t)sA * 3];  cyA = coords[(size_t)sA * 3 + 1]; czA = coords[(size_t)sA * 3 + 2];
    cxB = coords[(size_t)sB * 3];  cyB = coords[(size_t)sB * 3 + 1]; czB = coords[(size_t)sB * 3 + 2];
  }
#pragma unroll
  for (int m = 1; m < 64; m <<= 1) {
    cxA += __shfl_xor(cxA, m, 64); cyA += __shfl_xor(cyA, m, 64); czA += __shfl_xor(czA, m, 64);
    cxB += __shfl_xor(cxB, m, 64); cyB += __shfl_xor(cyB, m, 64); czB += __shfl_xor(czB, m, 64);
  }
  const float inv33 = 1.0f / 33.0f;
  aggA *= inv33; aggB *= inv33;
  cxA *= inv33; cyA *= inv33; czA *= inv33;
  cxB *= inv33; cyB *= inv33; czB *= inv33;

  float t1a = bsg[lane], t1b = t1a;
#pragma unroll 8
  for (int c = 0; c < 64; ++c) {
    float w = Wsg[c * 64 + lane];
    t1a += __shfl(aggA, c, 64) * w;
    t1b += __shfl(aggB, c, 64) * w;
  }
  {
    float w64 = Wsg[64 * 64 + lane], w65 = Wsg[65 * 64 + lane], w66 = Wsg[66 * 64 + lane];
    t1a += cxA * w64 + cyA * w65 + czA * w66;
    t1b += cxB * w64 + cyB * w65 + czB * w66;
  }
  t1a = fmaxf(t1a, 0.f); t1b = fmaxf(t1b, 0.f);

  float t2a = bf[lane], t2b = t2a;
#pragma unroll 8
  for (int c = 0; c < 64; ++c) {
    float w = Wf[c * 64 + lane];
    t2a += __shfl(t1a, c, 64) * w;
    t2b += __shfl(t1b, c, 64) * w;
  }

  float xa = t2a + hA, xb = t2b + hB;
  float sa = xa, sa2 = xa * xa, sb = xb, sb2 = xb * xb;
#pragma unroll
  for (int m = 1; m < 64; m <<= 1) {
    sa += __shfl_xor(sa, m, 64);  sa2 += __shfl_xor(sa2, m, 64);
    sb += __shfl_xor(sb, m, 64);  sb2 += __shfl_xor(sb2, m, 64);
  }
  float ma = sa * (1.f / 64.f), va = sa2 * (1.f / 64.f) - ma * ma;
  float mb = sb * (1.f / 64.f), vb = sb2 * (1.f / 64.f) - mb * mb;
  float gl = g_ff[lane], bl = b_ff[lane];
  out[(size_t)p0 * 64 + lane] = gl * (xa - ma) * rsqrtf(va + EPSF) + bl;
  out[(size_t)p1 * 64 + lane] = gl * (xb - mb) * rsqrtf(vb + EPSF) + bl;
}

extern "C" void kernel_launch(void* const* d_in, const int* in_sizes, int n_in,
                              void* d_out, int out_size, void* d_ws, size_t ws_size,
                              hipStream_t stream) {
  (void)in_sizes; (void)n_in; (void)out_size; (void)ws_size;
  const float* coords = (const float*)d_in[0];
  const float* feats  = (const float*)d_in[1];
  const float* Wq  = (const float*)d_in[2];  const float* bq  = (const float*)d_in[3];
  const float* Wk  = (const float*)d_in[4];  const float* bk  = (const float*)d_in[5];
  const float* Wv  = (const float*)d_in[6];  const float* bv  = (const float*)d_in[7];
  const float* Wl1 = (const float*)d_in[8];  const float* bl1 = (const float*)d_in[9];
  const float* Wl2 = (const float*)d_in[10]; const float* bl2 = (const float*)d_in[11];
  const float* Ww1 = (const float*)d_in[12]; const float* bw1 = (const float*)d_in[13];
  const float* Ww2 = (const float*)d_in[14]; const float* bw2 = (const float*)d_in[15];
  const float* g_att = (const float*)d_in[16]; const float* b_att = (const float*)d_in[17];
  const float* Wsg = (const float*)d_in[18]; const float* bsg = (const float*)d_in[19];
  const float* Wf  = (const float*)d_in[20]; const float* bf  = (const float*)d_in[21];
  const float* g_ff = (const float*)d_in[22]; const float* b_ff = (const float*)d_in[23];
  const int* knn = (const int*)d_in[24];

  // ws: [0, 2.56MB) h fp16 | [2.56MB, +48KB) swizzled weights | then Qh fp16
  _Float16* h   = (_Float16*)d_ws;
  _Float16* wtg = (_Float16*)((char*)d_ws + 2621440);
  _Float16* Qh  = (_Float16*)((char*)d_ws + 2621440 + 49152);
  float* out = (float*)d_out;

  prep_weights<<<dim3(6), dim3(256), 0, stream>>>(Wl2, Wv, Wk, Ww1, Ww2, Wq, wtg);
  q_kernel<<<dim3(157), dim3(256), 0, stream>>>(feats, bq, wtg, Qh);
  attn_kernel<<<dim3(NPTS / 4), dim3(256), 0, stream>>>(
      coords, feats, bk, bv, Wl1, bl1, bl2, bw1, bw2,
      g_att, b_att, knn, wtg, Qh, h);
  gconv_kernel<<<dim3(2500), dim3(256), 0, stream>>>(
      coords, h, Wsg, bsg, Wf, bf, g_ff, b_ff, knn, out);
}

// Round 4
// 230.047 us; speedup vs baseline: 4.1316x; 1.0660x over previous
//
#include <hip/hip_runtime.h>

#define NPTS 20000
#define EPSF 1e-5f

typedef _Float16 half8 __attribute__((ext_vector_type(8)));
typedef float floatx4 __attribute__((ext_vector_type(4)));

// ---------------------------------------------------------------------------
// B-fragment: frag[j] = W[32ks+8g+j][16nt+c15], from swizzled fp16 weights:
//   [k][d] -> d*64 + (((k>>3)^(d&7))<<3) + (k&7)
// ---------------------------------------------------------------------------
__device__ __forceinline__ half8 ldWt(const _Float16* __restrict__ w,
                                      int c15, int g, int nt, int ks) {
  int c = nt * 16 + c15;
  int kg = ks * 4 + g;
  return *(const half8*)(w + c * 64 + ((kg ^ (c & 7)) << 3));
}

// B-fragment directly from fp32 row-major W (one-shot use, L2-hot)
__device__ __forceinline__ half8 ldWtF32(const float* __restrict__ W,
                                         int c15, int g, int nt, int ks) {
  int c = nt * 16 + c15;
  half8 r;
#pragma unroll
  for (int j = 0; j < 8; ++j) r[j] = (_Float16)W[(ks * 32 + g * 8 + j) * 64 + c];
  return r;
}

// Per-wave transpose buffer T: 64 cols x 32 rows fp32, XOR-swizzled chunks:
// [col][row] -> col*32 + (((row>>2)^(col&7))<<2) + (row&3)
__device__ __forceinline__ void stC(float* __restrict__ Tw, int c15, int g,
                                    int mt, int nt, floatx4 v) {
  int col = nt * 16 + c15;
  int chunk = mt * 4 + g;
  *(floatx4*)(Tw + col * 32 + ((chunk ^ (col & 7)) << 2)) = v;
}

__device__ __forceinline__ floatx4 ldCread(const float* __restrict__ Tw,
                                           int c15, int g, int mt, int nt) {
  int col = nt * 16 + c15;
  int chunk = mt * 4 + g;
  return *(const floatx4*)(Tw + col * 32 + ((chunk ^ (col & 7)) << 2));
}

// A-fragment from T: frag[j] = X[16mt+c15][32ks+8g+j] (fp32 -> fp16)
__device__ __forceinline__ half8 ldA(const float* __restrict__ Tw,
                                     int c15, int g, int mt, int ks) {
  int m = mt * 16 + c15;
  half8 r;
#pragma unroll
  for (int j = 0; j < 8; ++j) {
    int c = ks * 32 + g * 8 + j;                // c&7 == j
    r[j] = (_Float16)Tw[c * 32 + (((m >> 2) ^ j) << 2) + (m & 3)];
  }
  return r;
}

__device__ __forceinline__ void ldAfrags(const float* __restrict__ Tw,
                                         int c15, int g, half8 a[2][2]) {
#pragma unroll
  for (int mt = 0; mt < 2; ++mt)
#pragma unroll
    for (int ks = 0; ks < 2; ++ks) a[mt][ks] = ldA(Tw, c15, g, mt, ks);
}

__device__ __forceinline__ void domm(const _Float16* __restrict__ w,
                                     const half8 a[2][2], int c15, int g,
                                     floatx4 acc[2][4]) {
#pragma unroll
  for (int ks = 0; ks < 2; ++ks)
#pragma unroll
    for (int nt = 0; nt < 4; ++nt) {
      half8 b = ldWt(w, c15, g, nt, ks);
#pragma unroll
      for (int mt = 0; mt < 2; ++mt)
        acc[mt][nt] = __builtin_amdgcn_mfma_f32_16x16x32_f16(a[mt][ks], b, acc[mt][nt], 0, 0, 0);
    }
}

// ---------------------------------------------------------------------------
// Fused weight-prep (blocks 0..6) + Q precompute (blocks 7..163).
// prep order: Wl2, Wv, Wk, Ww1, Ww2, Wsg[0:64], Wf
// ---------------------------------------------------------------------------
__global__ __launch_bounds__(256) void prep_q_kernel(
    const float* __restrict__ Wl2, const float* __restrict__ Wv,
    const float* __restrict__ Wk, const float* __restrict__ Ww1,
    const float* __restrict__ Ww2, const float* __restrict__ Wsg,
    const float* __restrict__ Wf, const float* __restrict__ Wq,
    const float* __restrict__ feats, const float* __restrict__ bq,
    _Float16* __restrict__ wtg, _Float16* __restrict__ Qh)
{
  if (blockIdx.x < 7) {
    const float* srcs[7] = {Wl2, Wv, Wk, Ww1, Ww2, Wsg, Wf};
    const float* src = srcs[blockIdx.x];
    _Float16* dst = wtg + blockIdx.x * 4096;
    int t = threadIdx.x;
#pragma unroll
    for (int i = 0; i < 16; ++i) {
      int lin = i * 256 + t;            // = k*64 + d
      int k = lin >> 6, d = lin & 63;
      dst[d * 64 + (((k >> 3) ^ (d & 7)) << 3) + (k & 7)] = (_Float16)src[lin];
    }
    return;
  }
  // ---- Q = relu(feats @ Wq + bq), 32 points/wave ----
  const int wv = threadIdx.x >> 6, lane = threadIdx.x & 63;
  const int c15 = lane & 15, g = lane >> 4;
  const int n0 = ((blockIdx.x - 7) * 4 + wv) * 32;

  half8 a[2][2];
#pragma unroll
  for (int mt = 0; mt < 2; ++mt) {
    int r = n0 + mt * 16 + c15;
    if (r > NPTS - 1) r = NPTS - 1;
#pragma unroll
    for (int ks = 0; ks < 2; ++ks) {
      const float* p = feats + (size_t)r * 64 + ks * 32 + g * 8;
      float4 u0 = *(const float4*)p, u1 = *(const float4*)(p + 4);
      a[mt][ks][0] = (_Float16)u0.x; a[mt][ks][1] = (_Float16)u0.y;
      a[mt][ks][2] = (_Float16)u0.z; a[mt][ks][3] = (_Float16)u0.w;
      a[mt][ks][4] = (_Float16)u1.x; a[mt][ks][5] = (_Float16)u1.y;
      a[mt][ks][6] = (_Float16)u1.z; a[mt][ks][7] = (_Float16)u1.w;
    }
  }
  floatx4 acc[2][4] = {};
#pragma unroll
  for (int ks = 0; ks < 2; ++ks)
#pragma unroll
    for (int nt = 0; nt < 4; ++nt) {
      half8 b = ldWtF32(Wq, c15, g, nt, ks);
#pragma unroll
      for (int mt = 0; mt < 2; ++mt)
        acc[mt][nt] = __builtin_amdgcn_mfma_f32_16x16x32_f16(a[mt][ks], b, acc[mt][nt], 0, 0, 0);
    }
#pragma unroll
  for (int nt = 0; nt < 4; ++nt) {
    float bqv = bq[nt * 16 + c15];
#pragma unroll
    for (int mt = 0; mt < 2; ++mt)
#pragma unroll
      for (int r = 0; r < 4; ++r) {
        int n = n0 + mt * 16 + g * 4 + r;
        if (n < NPTS)
          Qh[(size_t)n * 64 + nt * 16 + c15] = (_Float16)fmaxf(acc[mt][nt][r] + bqv, 0.f);
      }
  }
}

// ---------------------------------------------------------------------------
// Kernel A: fused per-point attention; one wave per point, MFMA matmuls.
// V is computed AFTER the sort so {fc,KR} is the only 2-acc overlap (~95 regs
// peak -> fits the 128-reg cap of (256,4) without scratch spills).
// ---------------------------------------------------------------------------
__global__ __launch_bounds__(256, 4) void attn_kernel(
    const float* __restrict__ coords, const float* __restrict__ feats,
    const float* __restrict__ bk, const float* __restrict__ bv,
    const float* __restrict__ Wl1, const float* __restrict__ bl1,
    const float* __restrict__ bl2, const float* __restrict__ bw1,
    const float* __restrict__ bw2, const float* __restrict__ g_att,
    const float* __restrict__ b_att, const int* __restrict__ knn,
    const _Float16* __restrict__ wtg, const _Float16* __restrict__ Qh,
    _Float16* __restrict__ h_out)
{
  __shared__ float Tsh[4][2048];
  const int wv = threadIdx.x >> 6, lane = threadIdx.x & 63;
  const int c15 = lane & 15, g = lane >> 4;
  const int n = blockIdx.x * 4 + wv;
  float* Tw = Tsh[wv];
  const int* row = knn + (size_t)n * 33;

  const _Float16* wt_l2 = wtg;
  const _Float16* wt_v  = wtg + 4096;
  const _Float16* wt_k  = wtg + 8192;
  const _Float16* wt_w1 = wtg + 12288;
  const _Float16* wt_w2 = wtg + 16384;

  // ---- h1 = relu(diff @ Wl1 + bl1), built directly in A-layout ----
  half8 aH[2][2];
  {
    float cnx = coords[(size_t)n * 3], cny = coords[(size_t)n * 3 + 1],
          cnz = coords[(size_t)n * 3 + 2];
#pragma unroll
    for (int ks = 0; ks < 2; ++ks) {
      int c0 = ks * 32 + g * 8;
      float4 wx0 = *(const float4*)(Wl1 + c0),       wx1 = *(const float4*)(Wl1 + c0 + 4);
      float4 wy0 = *(const float4*)(Wl1 + 64 + c0),  wy1 = *(const float4*)(Wl1 + 64 + c0 + 4);
      float4 wz0 = *(const float4*)(Wl1 + 128 + c0), wz1 = *(const float4*)(Wl1 + 128 + c0 + 4);
      float4 bb0 = *(const float4*)(bl1 + c0),       bb1 = *(const float4*)(bl1 + c0 + 4);
      float wx[8] = {wx0.x,wx0.y,wx0.z,wx0.w,wx1.x,wx1.y,wx1.z,wx1.w};
      float wy[8] = {wy0.x,wy0.y,wy0.z,wy0.w,wy1.x,wy1.y,wy1.z,wy1.w};
      float wz[8] = {wz0.x,wz0.y,wz0.z,wz0.w,wz1.x,wz1.y,wz1.z,wz1.w};
      float bb[8] = {bb0.x,bb0.y,bb0.z,bb0.w,bb1.x,bb1.y,bb1.z,bb1.w};
#pragma unroll
      for (int mt = 0; mt < 2; ++mt) {
        int id = row[mt * 16 + c15];
        float dx = coords[(size_t)id * 3] - cnx;
        float dy = coords[(size_t)id * 3 + 1] - cny;
        float dz = coords[(size_t)id * 3 + 2] - cnz;
#pragma unroll
        for (int j = 0; j < 8; ++j)
          aH[mt][ks][j] = (_Float16)fmaxf(dx * wx[j] + dy * wy[j] + dz * wz[j] + bb[j], 0.f);
      }
    }
  }

  // ---- fc = h1 @ Wl2 + bl2 ----
  floatx4 fc[2][4] = {};
  domm(wt_l2, aH, c15, g, fc);
#pragma unroll
  for (int nt = 0; nt < 4; ++nt) {
    float b = bl2[nt * 16 + c15];
#pragma unroll
    for (int mt = 0; mt < 2; ++mt) fc[mt][nt] += b;
  }

  // ---- pe = fc + feats[idx] -> T; aP frags ----
#pragma unroll
  for (int mt = 0; mt < 2; ++mt) {
    int idr[4];
#pragma unroll
    for (int r = 0; r < 4; ++r) idr[r] = row[mt * 16 + g * 4 + r];
#pragma unroll
    for (int nt = 0; nt < 4; ++nt) {
      floatx4 pe;
#pragma unroll
      for (int r = 0; r < 4; ++r)
        pe[r] = fc[mt][nt][r] + feats[(size_t)idr[r] * 64 + nt * 16 + c15];
      stC(Tw, c15, g, mt, nt, pe);
    }
  }
  __builtin_amdgcn_wave_barrier();
  half8 aP[2][2];
  ldAfrags(Tw, c15, g, aP);

  // ---- KR = pe @ Wk ; rel = (relu(KR+bk) - Q) * fc -> T ----
  {
    floatx4 KR[2][4] = {};
    domm(wt_k, aP, c15, g, KR);
    __builtin_amdgcn_wave_barrier();
#pragma unroll
    for (int nt = 0; nt < 4; ++nt) {
      float bkv = bk[nt * 16 + c15];
      float q4 = (float)Qh[(size_t)n * 64 + nt * 16 + c15];
#pragma unroll
      for (int mt = 0; mt < 2; ++mt) {
        floatx4 v;
#pragma unroll
        for (int r = 0; r < 4; ++r)
          v[r] = (fmaxf(KR[mt][nt][r] + bkv, 0.f) - q4) * fc[mt][nt][r];
        stC(Tw, c15, g, mt, nt, v);
      }
    }
  }
  __builtin_amdgcn_wave_barrier();
  half8 aR[2][2];
  ldAfrags(Tw, c15, g, aR);

  // ---- w1 = relu(rel @ Ww1 + bw1) -> T  (fc dead after this point) ----
  {
    floatx4 W1[2][4] = {};
    domm(wt_w1, aR, c15, g, W1);
    __builtin_amdgcn_wave_barrier();
#pragma unroll
    for (int nt = 0; nt < 4; ++nt) {
      float b = bw1[nt * 16 + c15];
#pragma unroll
      for (int mt = 0; mt < 2; ++mt) {
        floatx4 v;
#pragma unroll
        for (int r = 0; r < 4; ++r) v[r] = fmaxf(W1[mt][nt][r] + b, 0.f);
        stC(Tw, c15, g, mt, nt, v);
      }
    }
  }
  __builtin_amdgcn_wave_barrier();
  half8 aW[2][2];
  ldAfrags(Tw, c15, g, aW);

  // ---- w = w1 @ Ww2 + bw2 -> T ----
  {
    floatx4 WW[2][4] = {};
    domm(wt_w2, aW, c15, g, WW);
    __builtin_amdgcn_wave_barrier();
#pragma unroll
    for (int nt = 0; nt < 4; ++nt) {
      float b = bw2[nt * 16 + c15];
#pragma unroll
      for (int mt = 0; mt < 2; ++mt) stC(Tw, c15, g, mt, nt, WW[mt][nt] + b);
    }
  }
  __builtin_amdgcn_wave_barrier();

  // ---- sparsemax: lane d = lane sorts column d (from T) ----
  float tau;
  {
    float a[32];
#pragma unroll
    for (int i = 0; i < 8; ++i) {
      floatx4 ch = *(const floatx4*)(Tw + lane * 32 + ((i ^ (lane & 7)) << 2));
#pragma unroll
      for (int r = 0; r < 4; ++r) a[i * 4 + r] = ch[r];
    }
#pragma unroll
    for (int size = 2; size <= 32; size <<= 1) {
#pragma unroll
      for (int stride = size >> 1; stride > 0; stride >>= 1) {
#pragma unroll
        for (int i = 0; i < 32; ++i) {
          int j = i ^ stride;
          if (j > i) {
            float x = a[i], y = a[j];
            float lo = fminf(x, y), hi = fmaxf(x, y);
            bool up = ((i & size) == 0);
            a[i] = up ? hi : lo;
            a[j] = up ? lo : hi;
          }
        }
      }
    }
    float csum = 0.f, csel = 0.f;
    int ksup = 1;
#pragma unroll
    for (int i = 0; i < 32; ++i) {
      csum += a[i];
      if (1.0f + (float)(i + 1) * a[i] > csum) { ksup = i + 1; csel = csum; }
    }
    tau = (csel - 1.0f) / (float)ksup;
  }

  // ---- V = pe @ Wv + bv (aP still live; sort regs dead) ----
  floatx4 V[2][4] = {};
  domm(wt_v, aP, c15, g, V);
#pragma unroll
  for (int nt = 0; nt < 4; ++nt) {
    float b = bv[nt * 16 + c15];
#pragma unroll
    for (int mt = 0; mt < 2; ++mt) V[mt][nt] += b;
  }

  // ---- attn = sum_k max(w - tau, 0) * V ; x_att = 2*feats + attn; LN ----
  float x4[4];
#pragma unroll
  for (int nt = 0; nt < 4; ++nt) {
    float t4 = __shfl(tau, nt * 16 + c15, 64);
    float ssum = 0.f;
#pragma unroll
    for (int mt = 0; mt < 2; ++mt) {
      floatx4 w4 = ldCread(Tw, c15, g, mt, nt);
#pragma unroll
      for (int r = 0; r < 4; ++r)
        ssum += fmaxf(w4[r] - t4, 0.f) * V[mt][nt][r];
    }
    ssum += __shfl_xor(ssum, 16, 64);
    ssum += __shfl_xor(ssum, 32, 64);
    x4[nt] = 2.f * feats[(size_t)n * 64 + nt * 16 + c15] + ssum;
  }

  float sum = x4[0] + x4[1] + x4[2] + x4[3];
  float sum2 = x4[0] * x4[0] + x4[1] * x4[1] + x4[2] * x4[2] + x4[3] * x4[3];
#pragma unroll
  for (int m = 1; m < 16; m <<= 1) {
    sum += __shfl_xor(sum, m, 64);
    sum2 += __shfl_xor(sum2, m, 64);
  }
  float mean = sum * (1.f / 64.f);
  float var = sum2 * (1.f / 64.f) - mean * mean;
  float inv = rsqrtf(var + EPSF);
  h_out[(size_t)n * 64 + lane] =
      (_Float16)(g_att[lane] * (x4[g] - mean) * inv + b_att[lane]);
}

// ---------------------------------------------------------------------------
// Kernel B: graph conv + FFN + LN via MFMA. One wave = 32 points.
// agg gathered directly in A-fragment layout (no transpose needed).
// ---------------------------------------------------------------------------
__global__ __launch_bounds__(256) void gconv_kernel(
    const float* __restrict__ coords, const _Float16* __restrict__ h,
    const _Float16* __restrict__ wtg, const float* __restrict__ Wsg,
    const float* __restrict__ bsg, const float* __restrict__ bf,
    const float* __restrict__ g_ff, const float* __restrict__ b_ff,
    const int* __restrict__ knn, float* __restrict__ out)
{
  __shared__ float Tsh[4][2048];
  const int wv = threadIdx.x >> 6, lane = threadIdx.x & 63;
  const int c15 = lane & 15, g = lane >> 4;
  const int wid = blockIdx.x * 4 + wv;
  if (wid >= (NPTS + 31) / 32) return;
  const int n0 = wid * 32;
  float* Tw = Tsh[wv];
  const _Float16* wt_sg = wtg + 5 * 4096;
  const _Float16* wt_f  = wtg + 6 * 4096;
  const float inv33 = 1.0f / 33.0f;

  // ---- gather: acc[mt][ks][j] = sum over {self, knn[1..32]} of h ----
  float acc[2][2][8] = {};
  float cxa[2], cya[2], cza[2];
#pragma unroll
  for (int mt = 0; mt < 2; ++mt) {
    int p = n0 + mt * 16 + c15;
    const int* row = knn + (size_t)p * 33;
#pragma unroll 11
    for (int k = 0; k < 33; ++k) {
      int idx = (k == 0) ? p : row[k];
      const _Float16* hp = h + (size_t)idx * 64 + g * 8;
      half8 v0 = *(const half8*)hp;
      half8 v1 = *(const half8*)(hp + 32);
#pragma unroll
      for (int j = 0; j < 8; ++j) {
        acc[mt][0][j] += (float)v0[j];
        acc[mt][1][j] += (float)v1[j];
      }
    }
    // coords aggregate: split neighbors across g, butterfly-reduce
    float sx = 0.f, sy = 0.f, sz = 0.f;
    for (int k = g; k < 33; k += 4) {
      int idx = (k == 0) ? p : row[k];
      sx += coords[(size_t)idx * 3];
      sy += coords[(size_t)idx * 3 + 1];
      sz += coords[(size_t)idx * 3 + 2];
    }
    sx += __shfl_xor(sx, 16, 64); sx += __shfl_xor(sx, 32, 64);
    sy += __shfl_xor(sy, 16, 64); sy += __shfl_xor(sy, 32, 64);
    sz += __shfl_xor(sz, 16, 64); sz += __shfl_xor(sz, 32, 64);
    cxa[mt] = sx * inv33; cya[mt] = sy * inv33; cza[mt] = sz * inv33;
  }

  half8 aA[2][2];
#pragma unroll
  for (int mt = 0; mt < 2; ++mt)
#pragma unroll
    for (int ks = 0; ks < 2; ++ks)
#pragma unroll
      for (int j = 0; j < 8; ++j)
        aA[mt][ks][j] = (_Float16)(acc[mt][ks][j] * inv33);

  // ---- t1 = relu(agg @ Wsg + coords-part + bsg) -> T ----
  {
    floatx4 C1[2][4] = {};
    domm(wt_sg, aA, c15, g, C1);
#pragma unroll
    for (int nt = 0; nt < 4; ++nt) {
      int col = nt * 16 + c15;
      float b = bsg[col];
      float w64 = Wsg[4096 + col], w65 = Wsg[4160 + col], w66 = Wsg[4224 + col];
#pragma unroll
      for (int mt = 0; mt < 2; ++mt) {
        floatx4 v;
#pragma unroll
        for (int r = 0; r < 4; ++r) {
          int src = g * 4 + r;                   // holder lane (c15=src, g=0)
          float cx = __shfl(cxa[mt], src, 64);
          float cy = __shfl(cya[mt], src, 64);
          float cz = __shfl(cza[mt], src, 64);
          v[r] = fmaxf(C1[mt][nt][r] + b + cx * w64 + cy * w65 + cz * w66, 0.f);
        }
        stC(Tw, c15, g, mt, nt, v);
      }
    }
  }
  __builtin_amdgcn_wave_barrier();
  half8 aT[2][2];
  ldAfrags(Tw, c15, g, aT);

  // ---- x = t1 @ Wf + bf + h_self; LN over d; store ----
  floatx4 C2[2][4] = {};
  domm(wt_f, aT, c15, g, C2);
#pragma unroll
  for (int nt = 0; nt < 4; ++nt) {
    float b = bf[nt * 16 + c15];
#pragma unroll
    for (int mt = 0; mt < 2; ++mt)
#pragma unroll
      for (int r = 0; r < 4; ++r)
        C2[mt][nt][r] += b + (float)h[(size_t)(n0 + mt * 16 + g * 4 + r) * 64 + nt * 16 + c15];
  }
#pragma unroll
  for (int mt = 0; mt < 2; ++mt)
#pragma unroll
    for (int r = 0; r < 4; ++r) {
      float s = C2[mt][0][r] + C2[mt][1][r] + C2[mt][2][r] + C2[mt][3][r];
      float s2 = C2[mt][0][r] * C2[mt][0][r] + C2[mt][1][r] * C2[mt][1][r] +
                 C2[mt][2][r] * C2[mt][2][r] + C2[mt][3][r] * C2[mt][3][r];
#pragma unroll
      for (int m = 1; m < 16; m <<= 1) {
        s += __shfl_xor(s, m, 64);
        s2 += __shfl_xor(s2, m, 64);
      }
      float mean = s * (1.f / 64.f);
      float var = s2 * (1.f / 64.f) - mean * mean;
      float inv = rsqrtf(var + EPSF);
      int prow = n0 + mt * 16 + g * 4 + r;
#pragma unroll
      for (int nt = 0; nt < 4; ++nt) {
        int col = nt * 16 + c15;
        out[(size_t)prow * 64 + col] =
            g_ff[col] * (C2[mt][nt][r] - mean) * inv + b_ff[col];
      }
    }
}

extern "C" void kernel_launch(void* const* d_in, const int* in_sizes, int n_in,
                              void* d_out, int out_size, void* d_ws, size_t ws_size,
                              hipStream_t stream) {
  (void)in_sizes; (void)n_in; (void)out_size; (void)ws_size;
  const float* coords = (const float*)d_in[0];
  const float* feats  = (const float*)d_in[1];
  const float* Wq  = (const float*)d_in[2];  const float* bq  = (const float*)d_in[3];
  const float* Wk  = (const float*)d_in[4];  const float* bk  = (const float*)d_in[5];
  const float* Wv  = (const float*)d_in[6];  const float* bv  = (const float*)d_in[7];
  const float* Wl1 = (const float*)d_in[8];  const float* bl1 = (const float*)d_in[9];
  const float* Wl2 = (const float*)d_in[10]; const float* bl2 = (const float*)d_in[11];
  const float* Ww1 = (const float*)d_in[12]; const float* bw1 = (const float*)d_in[13];
  const float* Ww2 = (const float*)d_in[14]; const float* bw2 = (const float*)d_in[15];
  const float* g_att = (const float*)d_in[16]; const float* b_att = (const float*)d_in[17];
  const float* Wsg = (const float*)d_in[18]; const float* bsg = (const float*)d_in[19];
  const float* Wf  = (const float*)d_in[20]; const float* bf  = (const float*)d_in[21];
  const float* g_ff = (const float*)d_in[22]; const float* b_ff = (const float*)d_in[23];
  const int* knn = (const int*)d_in[24];

  // ws: [0, 2.56MB) h fp16 | [2.56MB, +56KB) swizzled weights | Qh fp16
  _Float16* h   = (_Float16*)d_ws;
  _Float16* wtg = (_Float16*)((char*)d_ws + 2621440);
  _Float16* Qh  = (_Float16*)((char*)d_ws + 2621440 + 57344);
  float* out = (float*)d_out;

  prep_q_kernel<<<dim3(164), dim3(256), 0, stream>>>(
      Wl2, Wv, Wk, Ww1, Ww2, Wsg, Wf, Wq, feats, bq, wtg, Qh);
  attn_kernel<<<dim3(NPTS / 4), dim3(256), 0, stream>>>(
      coords, feats, bk, bv, Wl1, bl1, bl2, bw1, bw2,
      g_att, b_att, knn, wtg, Qh, h);
  gconv_kernel<<<dim3(157), dim3(256), 0, stream>>>(
      coords, h, wtg, Wsg, bsg, bf, g_ff, b_ff, knn, out);
}

// Round 5
// 218.947 us; speedup vs baseline: 4.3411x; 1.0507x over previous
//
#include <hip/hip_runtime.h>

#define NPTS 20000
#define EPSF 1e-5f

typedef _Float16 half8 __attribute__((ext_vector_type(8)));
typedef float floatx4 __attribute__((ext_vector_type(4)));

// ---------------------------------------------------------------------------
// B-fragment: frag[j] = W[32ks+8g+j][16nt+c15], from swizzled fp16 weights:
//   [k][d] -> d*64 + (((k>>3)^(d&7))<<3) + (k&7)
// ---------------------------------------------------------------------------
__device__ __forceinline__ half8 ldWt(const _Float16* __restrict__ w,
                                      int c15, int g, int nt, int ks) {
  int c = nt * 16 + c15;
  int kg = ks * 4 + g;
  return *(const half8*)(w + c * 64 + ((kg ^ (c & 7)) << 3));
}

// B-fragment directly from fp32 row-major W (one-shot use, L2-hot)
__device__ __forceinline__ half8 ldWtF32(const float* __restrict__ W,
                                         int c15, int g, int nt, int ks) {
  int c = nt * 16 + c15;
  half8 r;
#pragma unroll
  for (int j = 0; j < 8; ++j) r[j] = (_Float16)W[(ks * 32 + g * 8 + j) * 64 + c];
  return r;
}

// Per-wave transpose buffer T: 64 cols x 32 rows fp32, XOR-swizzled chunks:
// [col][row] -> col*32 + (((row>>2)^(col&7))<<2) + (row&3)
__device__ __forceinline__ void stC(float* __restrict__ Tw, int c15, int g,
                                    int mt, int nt, floatx4 v) {
  int col = nt * 16 + c15;
  int chunk = mt * 4 + g;
  *(floatx4*)(Tw + col * 32 + ((chunk ^ (col & 7)) << 2)) = v;
}

__device__ __forceinline__ floatx4 ldCread(const float* __restrict__ Tw,
                                           int c15, int g, int mt, int nt) {
  int col = nt * 16 + c15;
  int chunk = mt * 4 + g;
  return *(const floatx4*)(Tw + col * 32 + ((chunk ^ (col & 7)) << 2));
}

// A-fragment from T: frag[j] = X[16mt+c15][32ks+8g+j] (fp32 -> fp16)
__device__ __forceinline__ half8 ldA(const float* __restrict__ Tw,
                                     int c15, int g, int mt, int ks) {
  int m = mt * 16 + c15;
  half8 r;
#pragma unroll
  for (int j = 0; j < 8; ++j) {
    int c = ks * 32 + g * 8 + j;                // c&7 == j
    r[j] = (_Float16)Tw[c * 32 + (((m >> 2) ^ j) << 2) + (m & 3)];
  }
  return r;
}

__device__ __forceinline__ void ldAfrags(const float* __restrict__ Tw,
                                         int c15, int g, half8 a[2][2]) {
#pragma unroll
  for (int mt = 0; mt < 2; ++mt)
#pragma unroll
    for (int ks = 0; ks < 2; ++ks) a[mt][ks] = ldA(Tw, c15, g, mt, ks);
}

__device__ __forceinline__ void domm(const _Float16* __restrict__ w,
                                     const half8 a[2][2], int c15, int g,
                                     floatx4 acc[2][4]) {
#pragma unroll
  for (int ks = 0; ks < 2; ++ks)
#pragma unroll
    for (int nt = 0; nt < 4; ++nt) {
      half8 b = ldWt(w, c15, g, nt, ks);
#pragma unroll
      for (int mt = 0; mt < 2; ++mt)
        acc[mt][nt] = __builtin_amdgcn_mfma_f32_16x16x32_f16(a[mt][ks], b, acc[mt][nt], 0, 0, 0);
    }
}

// single-mt (16-row) variant for gconv
__device__ __forceinline__ void domm1(const _Float16* __restrict__ w,
                                      const half8 a[2], int c15, int g,
                                      floatx4 acc[4]) {
#pragma unroll
  for (int ks = 0; ks < 2; ++ks)
#pragma unroll
    for (int nt = 0; nt < 4; ++nt) {
      half8 b = ldWt(w, c15, g, nt, ks);
      acc[nt] = __builtin_amdgcn_mfma_f32_16x16x32_f16(a[ks], b, acc[nt], 0, 0, 0);
    }
}

// ---------------------------------------------------------------------------
// Fused weight-prep (blocks 0..6) + Q precompute (blocks 7..163).
// prep order: Wl2, Wv, Wk, Ww1, Ww2, Wsg[0:64], Wf
// ---------------------------------------------------------------------------
__global__ __launch_bounds__(256) void prep_q_kernel(
    const float* __restrict__ Wl2, const float* __restrict__ Wv,
    const float* __restrict__ Wk, const float* __restrict__ Ww1,
    const float* __restrict__ Ww2, const float* __restrict__ Wsg,
    const float* __restrict__ Wf, const float* __restrict__ Wq,
    const float* __restrict__ feats, const float* __restrict__ bq,
    _Float16* __restrict__ wtg, _Float16* __restrict__ Qh)
{
  if (blockIdx.x < 7) {
    const float* srcs[7] = {Wl2, Wv, Wk, Ww1, Ww2, Wsg, Wf};
    const float* src = srcs[blockIdx.x];
    _Float16* dst = wtg + blockIdx.x * 4096;
    int t = threadIdx.x;
#pragma unroll
    for (int i = 0; i < 16; ++i) {
      int lin = i * 256 + t;            // = k*64 + d
      int k = lin >> 6, d = lin & 63;
      dst[d * 64 + (((k >> 3) ^ (d & 7)) << 3) + (k & 7)] = (_Float16)src[lin];
    }
    return;
  }
  // ---- Q = relu(feats @ Wq + bq), 32 points/wave ----
  const int wv = threadIdx.x >> 6, lane = threadIdx.x & 63;
  const int c15 = lane & 15, g = lane >> 4;
  const int n0 = ((blockIdx.x - 7) * 4 + wv) * 32;

  half8 a[2][2];
#pragma unroll
  for (int mt = 0; mt < 2; ++mt) {
    int r = n0 + mt * 16 + c15;
    if (r > NPTS - 1) r = NPTS - 1;
#pragma unroll
    for (int ks = 0; ks < 2; ++ks) {
      const float* p = feats + (size_t)r * 64 + ks * 32 + g * 8;
      float4 u0 = *(const float4*)p, u1 = *(const float4*)(p + 4);
      a[mt][ks][0] = (_Float16)u0.x; a[mt][ks][1] = (_Float16)u0.y;
      a[mt][ks][2] = (_Float16)u0.z; a[mt][ks][3] = (_Float16)u0.w;
      a[mt][ks][4] = (_Float16)u1.x; a[mt][ks][5] = (_Float16)u1.y;
      a[mt][ks][6] = (_Float16)u1.z; a[mt][ks][7] = (_Float16)u1.w;
    }
  }
  floatx4 acc[2][4] = {};
#pragma unroll
  for (int ks = 0; ks < 2; ++ks)
#pragma unroll
    for (int nt = 0; nt < 4; ++nt) {
      half8 b = ldWtF32(Wq, c15, g, nt, ks);
#pragma unroll
      for (int mt = 0; mt < 2; ++mt)
        acc[mt][nt] = __builtin_amdgcn_mfma_f32_16x16x32_f16(a[mt][ks], b, acc[mt][nt], 0, 0, 0);
    }
#pragma unroll
  for (int nt = 0; nt < 4; ++nt) {
    float bqv = bq[nt * 16 + c15];
#pragma unroll
    for (int mt = 0; mt < 2; ++mt)
#pragma unroll
      for (int r = 0; r < 4; ++r) {
        int n = n0 + mt * 16 + g * 4 + r;
        if (n < NPTS)
          Qh[(size_t)n * 64 + nt * 16 + c15] = (_Float16)fmaxf(acc[mt][nt][r] + bqv, 0.f);
      }
  }
}

// ---------------------------------------------------------------------------
// Kernel A: fused per-point attention; one wave per point, MFMA matmuls.
// (256,3): 170 unified regs/wave -> no scratch spills (R4's (256,4)=128 regs
// spilled ~46 MB to scratch; spill traffic was ~70% of attn's HBM bytes).
// ---------------------------------------------------------------------------
__global__ __launch_bounds__(256, 3) void attn_kernel(
    const float* __restrict__ coords, const float* __restrict__ feats,
    const float* __restrict__ bk, const float* __restrict__ bv,
    const float* __restrict__ Wl1, const float* __restrict__ bl1,
    const float* __restrict__ bl2, const float* __restrict__ bw1,
    const float* __restrict__ bw2, const float* __restrict__ g_att,
    const float* __restrict__ b_att, const int* __restrict__ knn,
    const _Float16* __restrict__ wtg, const _Float16* __restrict__ Qh,
    _Float16* __restrict__ h_out)
{
  __shared__ float Tsh[4][2048];
  const int wv = threadIdx.x >> 6, lane = threadIdx.x & 63;
  const int c15 = lane & 15, g = lane >> 4;
  const int n = blockIdx.x * 4 + wv;
  float* Tw = Tsh[wv];
  const int* row = knn + (size_t)n * 33;

  const _Float16* wt_l2 = wtg;
  const _Float16* wt_v  = wtg + 4096;
  const _Float16* wt_k  = wtg + 8192;
  const _Float16* wt_w1 = wtg + 12288;
  const _Float16* wt_w2 = wtg + 16384;

  // ---- h1 = relu(diff @ Wl1 + bl1), built directly in A-layout ----
  half8 aH[2][2];
  {
    float cnx = coords[(size_t)n * 3], cny = coords[(size_t)n * 3 + 1],
          cnz = coords[(size_t)n * 3 + 2];
#pragma unroll
    for (int ks = 0; ks < 2; ++ks) {
      int c0 = ks * 32 + g * 8;
      float4 wx0 = *(const float4*)(Wl1 + c0),       wx1 = *(const float4*)(Wl1 + c0 + 4);
      float4 wy0 = *(const float4*)(Wl1 + 64 + c0),  wy1 = *(const float4*)(Wl1 + 64 + c0 + 4);
      float4 wz0 = *(const float4*)(Wl1 + 128 + c0), wz1 = *(const float4*)(Wl1 + 128 + c0 + 4);
      float4 bb0 = *(const float4*)(bl1 + c0),       bb1 = *(const float4*)(bl1 + c0 + 4);
      float wx[8] = {wx0.x,wx0.y,wx0.z,wx0.w,wx1.x,wx1.y,wx1.z,wx1.w};
      float wy[8] = {wy0.x,wy0.y,wy0.z,wy0.w,wy1.x,wy1.y,wy1.z,wy1.w};
      float wz[8] = {wz0.x,wz0.y,wz0.z,wz0.w,wz1.x,wz1.y,wz1.z,wz1.w};
      float bb[8] = {bb0.x,bb0.y,bb0.z,bb0.w,bb1.x,bb1.y,bb1.z,bb1.w};
#pragma unroll
      for (int mt = 0; mt < 2; ++mt) {
        int id = row[mt * 16 + c15];
        float dx = coords[(size_t)id * 3] - cnx;
        float dy = coords[(size_t)id * 3 + 1] - cny;
        float dz = coords[(size_t)id * 3 + 2] - cnz;
#pragma unroll
        for (int j = 0; j < 8; ++j)
          aH[mt][ks][j] = (_Float16)fmaxf(dx * wx[j] + dy * wy[j] + dz * wz[j] + bb[j], 0.f);
      }
    }
  }

  // ---- fc = h1 @ Wl2 + bl2 ----
  floatx4 fc[2][4] = {};
  domm(wt_l2, aH, c15, g, fc);
#pragma unroll
  for (int nt = 0; nt < 4; ++nt) {
    float b = bl2[nt * 16 + c15];
#pragma unroll
    for (int mt = 0; mt < 2; ++mt) fc[mt][nt] += b;
  }

  // ---- pe = fc + feats[idx] -> T; aP frags ----
#pragma unroll
  for (int mt = 0; mt < 2; ++mt) {
    int idr[4];
#pragma unroll
    for (int r = 0; r < 4; ++r) idr[r] = row[mt * 16 + g * 4 + r];
#pragma unroll
    for (int nt = 0; nt < 4; ++nt) {
      floatx4 pe;
#pragma unroll
      for (int r = 0; r < 4; ++r)
        pe[r] = fc[mt][nt][r] + feats[(size_t)idr[r] * 64 + nt * 16 + c15];
      stC(Tw, c15, g, mt, nt, pe);
    }
  }
  __builtin_amdgcn_wave_barrier();
  half8 aP[2][2];
  ldAfrags(Tw, c15, g, aP);

  // ---- KR = pe @ Wk ; rel = (relu(KR+bk) - Q) * fc -> T ----
  {
    floatx4 KR[2][4] = {};
    domm(wt_k, aP, c15, g, KR);
    __builtin_amdgcn_wave_barrier();
#pragma unroll
    for (int nt = 0; nt < 4; ++nt) {
      float bkv = bk[nt * 16 + c15];
      float q4 = (float)Qh[(size_t)n * 64 + nt * 16 + c15];
#pragma unroll
      for (int mt = 0; mt < 2; ++mt) {
        floatx4 v;
#pragma unroll
        for (int r = 0; r < 4; ++r)
          v[r] = (fmaxf(KR[mt][nt][r] + bkv, 0.f) - q4) * fc[mt][nt][r];
        stC(Tw, c15, g, mt, nt, v);
      }
    }
  }
  __builtin_amdgcn_wave_barrier();
  half8 aR[2][2];
  ldAfrags(Tw, c15, g, aR);

  // ---- w1 = relu(rel @ Ww1 + bw1) -> T  (fc dead after this point) ----
  {
    floatx4 W1[2][4] = {};
    domm(wt_w1, aR, c15, g, W1);
    __builtin_amdgcn_wave_barrier();
#pragma unroll
    for (int nt = 0; nt < 4; ++nt) {
      float b = bw1[nt * 16 + c15];
#pragma unroll
      for (int mt = 0; mt < 2; ++mt) {
        floatx4 v;
#pragma unroll
        for (int r = 0; r < 4; ++r) v[r] = fmaxf(W1[mt][nt][r] + b, 0.f);
        stC(Tw, c15, g, mt, nt, v);
      }
    }
  }
  __builtin_amdgcn_wave_barrier();
  half8 aW[2][2];
  ldAfrags(Tw, c15, g, aW);

  // ---- w = w1 @ Ww2 + bw2 -> T ----
  {
    floatx4 WW[2][4] = {};
    domm(wt_w2, aW, c15, g, WW);
    __builtin_amdgcn_wave_barrier();
#pragma unroll
    for (int nt = 0; nt < 4; ++nt) {
      float b = bw2[nt * 16 + c15];
#pragma unroll
      for (int mt = 0; mt < 2; ++mt) stC(Tw, c15, g, mt, nt, WW[mt][nt] + b);
    }
  }
  __builtin_amdgcn_wave_barrier();

  // ---- sparsemax: lane d = lane sorts column d (from T) ----
  float tau;
  {
    float a[32];
#pragma unroll
    for (int i = 0; i < 8; ++i) {
      floatx4 ch = *(const floatx4*)(Tw + lane * 32 + ((i ^ (lane & 7)) << 2));
#pragma unroll
      for (int r = 0; r < 4; ++r) a[i * 4 + r] = ch[r];
    }
#pragma unroll
    for (int size = 2; size <= 32; size <<= 1) {
#pragma unroll
      for (int stride = size >> 1; stride > 0; stride >>= 1) {
#pragma unroll
        for (int i = 0; i < 32; ++i) {
          int j = i ^ stride;
          if (j > i) {
            float x = a[i], y = a[j];
            float lo = fminf(x, y), hi = fmaxf(x, y);
            bool up = ((i & size) == 0);
            a[i] = up ? hi : lo;
            a[j] = up ? lo : hi;
          }
        }
      }
    }
    float csum = 0.f, csel = 0.f;
    int ksup = 1;
#pragma unroll
    for (int i = 0; i < 32; ++i) {
      csum += a[i];
      if (1.0f + (float)(i + 1) * a[i] > csum) { ksup = i + 1; csel = csum; }
    }
    tau = (csel - 1.0f) / (float)ksup;
  }

  // ---- V = pe @ Wv + bv (aP still live; sort regs dead) ----
  floatx4 V[2][4] = {};
  domm(wt_v, aP, c15, g, V);
#pragma unroll
  for (int nt = 0; nt < 4; ++nt) {
    float b = bv[nt * 16 + c15];
#pragma unroll
    for (int mt = 0; mt < 2; ++mt) V[mt][nt] += b;
  }

  // ---- attn = sum_k max(w - tau, 0) * V ; x_att = 2*feats + attn; LN ----
  float x4[4];
#pragma unroll
  for (int nt = 0; nt < 4; ++nt) {
    float t4 = __shfl(tau, nt * 16 + c15, 64);
    float ssum = 0.f;
#pragma unroll
    for (int mt = 0; mt < 2; ++mt) {
      floatx4 w4 = ldCread(Tw, c15, g, mt, nt);
#pragma unroll
      for (int r = 0; r < 4; ++r)
        ssum += fmaxf(w4[r] - t4, 0.f) * V[mt][nt][r];
    }
    ssum += __shfl_xor(ssum, 16, 64);
    ssum += __shfl_xor(ssum, 32, 64);
    x4[nt] = 2.f * feats[(size_t)n * 64 + nt * 16 + c15] + ssum;
  }

  float sum = x4[0] + x4[1] + x4[2] + x4[3];
  float sum2 = x4[0] * x4[0] + x4[1] * x4[1] + x4[2] * x4[2] + x4[3] * x4[3];
#pragma unroll
  for (int m = 1; m < 16; m <<= 1) {
    sum += __shfl_xor(sum, m, 64);
    sum2 += __shfl_xor(sum2, m, 64);
  }
  float mean = sum * (1.f / 64.f);
  float var = sum2 * (1.f / 64.f) - mean * mean;
  float inv = rsqrtf(var + EPSF);
  h_out[(size_t)n * 64 + lane] =
      (_Float16)(g_att[lane] * (x4[g] - mean) * inv + b_att[lane]);
}

// ---------------------------------------------------------------------------
// Kernel B: graph conv + FFN + LN via MFMA. One wave = 16 points
// (more waves than 32-pt version -> better gather-latency hiding).
// ---------------------------------------------------------------------------
__global__ __launch_bounds__(256) void gconv_kernel(
    const float* __restrict__ coords, const _Float16* __restrict__ h,
    const _Float16* __restrict__ wtg, const float* __restrict__ Wsg,
    const float* __restrict__ bsg, const float* __restrict__ bf,
    const float* __restrict__ g_ff, const float* __restrict__ b_ff,
    const int* __restrict__ knn, float* __restrict__ out)
{
  __shared__ float Tsh[4][2048];
  const int wv = threadIdx.x >> 6, lane = threadIdx.x & 63;
  const int c15 = lane & 15, g = lane >> 4;
  const int n0 = (blockIdx.x * 4 + wv) * 16;
  if (n0 >= NPTS) return;
  float* Tw = Tsh[wv];
  const _Float16* wt_sg = wtg + 5 * 4096;
  const _Float16* wt_f  = wtg + 6 * 4096;
  const float inv33 = 1.0f / 33.0f;

  // ---- gather in A-layout: point p = n0 + c15, cols g*8.. and 32+g*8.. ----
  const int p = n0 + c15;
  const int* row = knn + (size_t)p * 33;
  float acc0[8] = {}, acc1[8] = {};
#pragma unroll 11
  for (int k = 0; k < 33; ++k) {
    int idx = (k == 0) ? p : row[k];
    const _Float16* hp = h + (size_t)idx * 64 + g * 8;
    half8 v0 = *(const half8*)hp;
    half8 v1 = *(const half8*)(hp + 32);
#pragma unroll
    for (int j = 0; j < 8; ++j) {
      acc0[j] += (float)v0[j];
      acc1[j] += (float)v1[j];
    }
  }
  // coords aggregate: split neighbors across g, butterfly-reduce
  float sx = 0.f, sy = 0.f, sz = 0.f;
  for (int k = g; k < 33; k += 4) {
    int idx = (k == 0) ? p : row[k];
    sx += coords[(size_t)idx * 3];
    sy += coords[(size_t)idx * 3 + 1];
    sz += coords[(size_t)idx * 3 + 2];
  }
  sx += __shfl_xor(sx, 16, 64); sx += __shfl_xor(sx, 32, 64);
  sy += __shfl_xor(sy, 16, 64); sy += __shfl_xor(sy, 32, 64);
  sz += __shfl_xor(sz, 16, 64); sz += __shfl_xor(sz, 32, 64);
  float cxa = sx * inv33, cya = sy * inv33, cza = sz * inv33;

  half8 aA[2];
#pragma unroll
  for (int j = 0; j < 8; ++j) {
    aA[0][j] = (_Float16)(acc0[j] * inv33);
    aA[1][j] = (_Float16)(acc1[j] * inv33);
  }

  // ---- t1 = relu(agg @ Wsg + coords-part + bsg) -> T (16-row half) ----
  {
    floatx4 C1[4] = {};
    domm1(wt_sg, aA, c15, g, C1);
#pragma unroll
    for (int nt = 0; nt < 4; ++nt) {
      int col = nt * 16 + c15;
      float b = bsg[col];
      float w64 = Wsg[4096 + col], w65 = Wsg[4160 + col], w66 = Wsg[4224 + col];
      floatx4 v;
#pragma unroll
      for (int r = 0; r < 4; ++r) {
        int src = g * 4 + r;                  // holder lane for point n0+src
        float cx = __shfl(cxa, src, 64);
        float cy = __shfl(cya, src, 64);
        float cz = __shfl(cza, src, 64);
        v[r] = fmaxf(C1[nt][r] + b + cx * w64 + cy * w65 + cz * w66, 0.f);
      }
      stC(Tw, c15, g, 0, nt, v);
    }
  }
  __builtin_amdgcn_wave_barrier();
  half8 aT[2];
  aT[0] = ldA(Tw, c15, g, 0, 0);
  aT[1] = ldA(Tw, c15, g, 0, 1);

  // ---- x = t1 @ Wf + bf + h_self; LN over d; store ----
  floatx4 C2[4] = {};
  domm1(wt_f, aT, c15, g, C2);
#pragma unroll
  for (int nt = 0; nt < 4; ++nt) {
    float b = bf[nt * 16 + c15];
#pragma unroll
    for (int r = 0; r < 4; ++r)
      C2[nt][r] += b + (float)h[(size_t)(n0 + g * 4 + r) * 64 + nt * 16 + c15];
  }
#pragma unroll
  for (int r = 0; r < 4; ++r) {
    float s = C2[0][r] + C2[1][r] + C2[2][r] + C2[3][r];
    float s2 = C2[0][r] * C2[0][r] + C2[1][r] * C2[1][r] +
               C2[2][r] * C2[2][r] + C2[3][r] * C2[3][r];
#pragma unroll
    for (int m = 1; m < 16; m <<= 1) {
      s += __shfl_xor(s, m, 64);
      s2 += __shfl_xor(s2, m, 64);
    }
    float mean = s * (1.f / 64.f);
    float var = s2 * (1.f / 64.f) - mean * mean;
    float inv = rsqrtf(var + EPSF);
    int prow = n0 + g * 4 + r;
#pragma unroll
    for (int nt = 0; nt < 4; ++nt) {
      int col = nt * 16 + c15;
      out[(size_t)prow * 64 + col] =
          g_ff[col] * (C2[nt][r] - mean) * inv + b_ff[col];
    }
  }
}

extern "C" void kernel_launch(void* const* d_in, const int* in_sizes, int n_in,
                              void* d_out, int out_size, void* d_ws, size_t ws_size,
                              hipStream_t stream) {
  (void)in_sizes; (void)n_in; (void)out_size; (void)ws_size;
  const float* coords = (const float*)d_in[0];
  const float* feats  = (const float*)d_in[1];
  const float* Wq  = (const float*)d_in[2];  const float* bq  = (const float*)d_in[3];
  const float* Wk  = (const float*)d_in[4];  const float* bk  = (const float*)d_in[5];
  const float* Wv  = (const float*)d_in[6];  const float* bv  = (const float*)d_in[7];
  const float* Wl1 = (const float*)d_in[8];  const float* bl1 = (const float*)d_in[9];
  const float* Wl2 = (const float*)d_in[10]; const float* bl2 = (const float*)d_in[11];
  const float* Ww1 = (const float*)d_in[12]; const float* bw1 = (const float*)d_in[13];
  const float* Ww2 = (const float*)d_in[14]; const float* bw2 = (const float*)d_in[15];
  const float* g_att = (const float*)d_in[16]; const float* b_att = (const float*)d_in[17];
  const float* Wsg = (const float*)d_in[18]; const float* bsg = (const float*)d_in[19];
  const float* Wf  = (const float*)d_in[20]; const float* bf  = (const float*)d_in[21];
  const float* g_ff = (const float*)d_in[22]; const float* b_ff = (const float*)d_in[23];
  const int* knn = (const int*)d_in[24];

  // ws: [0, 2.56MB) h fp16 | [2.56MB, +56KB) swizzled weights | Qh fp16
  _Float16* h   = (_Float16*)d_ws;
  _Float16* wtg = (_Float16*)((char*)d_ws + 2621440);
  _Float16* Qh  = (_Float16*)((char*)d_ws + 2621440 + 57344);
  float* out = (float*)d_out;

  prep_q_kernel<<<dim3(164), dim3(256), 0, stream>>>(
      Wl2, Wv, Wk, Ww1, Ww2, Wsg, Wf, Wq, feats, bq, wtg, Qh);
  attn_kernel<<<dim3(NPTS / 4), dim3(256), 0, stream>>>(
      coords, feats, bk, bv, Wl1, bl1, bl2, bw1, bw2,
      g_att, b_att, knn, wtg, Qh, h);
  gconv_kernel<<<dim3(313), dim3(256), 0, stream>>>(
      coords, h, wtg, Wsg, bsg, bf, g_ff, b_ff, knn, out);
}

// Round 6
// 218.765 us; speedup vs baseline: 4.3447x; 1.0008x over previous
//
#include <hip/hip_runtime.h>

#define NPTS 20000
#define EPSF 1e-5f

typedef _Float16 half8 __attribute__((ext_vector_type(8)));
typedef float floatx4 __attribute__((ext_vector_type(4)));

// ---------------------------------------------------------------------------
// B-fragment: frag[j] = W[32ks+8g+j][16nt+c15], from swizzled fp16 weights:
//   [k][d] -> d*64 + (((k>>3)^(d&7))<<3) + (k&7)
// ---------------------------------------------------------------------------
__device__ __forceinline__ half8 ldWt(const _Float16* __restrict__ w,
                                      int c15, int g, int nt, int ks) {
  int c = nt * 16 + c15;
  int kg = ks * 4 + g;
  return *(const half8*)(w + c * 64 + ((kg ^ (c & 7)) << 3));
}

// B-fragment directly from fp32 row-major W (one-shot use, L2-hot)
__device__ __forceinline__ half8 ldWtF32(const float* __restrict__ W,
                                         int c15, int g, int nt, int ks) {
  int c = nt * 16 + c15;
  half8 r;
#pragma unroll
  for (int j = 0; j < 8; ++j) r[j] = (_Float16)W[(ks * 32 + g * 8 + j) * 64 + c];
  return r;
}

// Per-wave transpose buffer T: 64 cols x 32 rows fp32, XOR-swizzled chunks:
// [col][row] -> col*32 + (((row>>2)^(col&7))<<2) + (row&3)
__device__ __forceinline__ void stC(float* __restrict__ Tw, int c15, int g,
                                    int mt, int nt, floatx4 v) {
  int col = nt * 16 + c15;
  int chunk = mt * 4 + g;
  *(floatx4*)(Tw + col * 32 + ((chunk ^ (col & 7)) << 2)) = v;
}

__device__ __forceinline__ floatx4 ldCread(const float* __restrict__ Tw,
                                           int c15, int g, int mt, int nt) {
  int col = nt * 16 + c15;
  int chunk = mt * 4 + g;
  return *(const floatx4*)(Tw + col * 32 + ((chunk ^ (col & 7)) << 2));
}

// A-fragment from T: frag[j] = X[16mt+c15][32ks+8g+j] (fp32 -> fp16)
__device__ __forceinline__ half8 ldA(const float* __restrict__ Tw,
                                     int c15, int g, int mt, int ks) {
  int m = mt * 16 + c15;
  half8 r;
#pragma unroll
  for (int j = 0; j < 8; ++j) {
    int c = ks * 32 + g * 8 + j;                // c&7 == j
    r[j] = (_Float16)Tw[c * 32 + (((m >> 2) ^ j) << 2) + (m & 3)];
  }
  return r;
}

__device__ __forceinline__ void ldAfrags(const float* __restrict__ Tw,
                                         int c15, int g, half8 a[2][2]) {
#pragma unroll
  for (int mt = 0; mt < 2; ++mt)
#pragma unroll
    for (int ks = 0; ks < 2; ++ks) a[mt][ks] = ldA(Tw, c15, g, mt, ks);
}

__device__ __forceinline__ void domm(const _Float16* __restrict__ w,
                                     const half8 a[2][2], int c15, int g,
                                     floatx4 acc[2][4]) {
#pragma unroll
  for (int ks = 0; ks < 2; ++ks)
#pragma unroll
    for (int nt = 0; nt < 4; ++nt) {
      half8 b = ldWt(w, c15, g, nt, ks);
#pragma unroll
      for (int mt = 0; mt < 2; ++mt)
        acc[mt][nt] = __builtin_amdgcn_mfma_f32_16x16x32_f16(a[mt][ks], b, acc[mt][nt], 0, 0, 0);
    }
}

// single-mt (16-row) variant for gconv
__device__ __forceinline__ void domm1(const _Float16* __restrict__ w,
                                      const half8 a[2], int c15, int g,
                                      floatx4 acc[4]) {
#pragma unroll
  for (int ks = 0; ks < 2; ++ks)
#pragma unroll
    for (int nt = 0; nt < 4; ++nt) {
      half8 b = ldWt(w, c15, g, nt, ks);
      acc[nt] = __builtin_amdgcn_mfma_f32_16x16x32_f16(a[ks], b, acc[nt], 0, 0, 0);
    }
}

// ---------------------------------------------------------------------------
// Fused weight-prep (blocks 0..6) + Q precompute (blocks 7..163).
// prep order: Wl2, Wv, Wk, Ww1, Ww2, Wsg[0:64], Wf
// ---------------------------------------------------------------------------
__global__ __launch_bounds__(256) void prep_q_kernel(
    const float* __restrict__ Wl2, const float* __restrict__ Wv,
    const float* __restrict__ Wk, const float* __restrict__ Ww1,
    const float* __restrict__ Ww2, const float* __restrict__ Wsg,
    const float* __restrict__ Wf, const float* __restrict__ Wq,
    const float* __restrict__ feats, const float* __restrict__ bq,
    _Float16* __restrict__ wtg, _Float16* __restrict__ Qh)
{
  if (blockIdx.x < 7) {
    const float* srcs[7] = {Wl2, Wv, Wk, Ww1, Ww2, Wsg, Wf};
    const float* src = srcs[blockIdx.x];
    _Float16* dst = wtg + blockIdx.x * 4096;
    int t = threadIdx.x;
#pragma unroll
    for (int i = 0; i < 16; ++i) {
      int lin = i * 256 + t;            // = k*64 + d
      int k = lin >> 6, d = lin & 63;
      dst[d * 64 + (((k >> 3) ^ (d & 7)) << 3) + (k & 7)] = (_Float16)src[lin];
    }
    return;
  }
  // ---- Q = relu(feats @ Wq + bq), 32 points/wave ----
  const int wv = threadIdx.x >> 6, lane = threadIdx.x & 63;
  const int c15 = lane & 15, g = lane >> 4;
  const int n0 = ((blockIdx.x - 7) * 4 + wv) * 32;

  half8 a[2][2];
#pragma unroll
  for (int mt = 0; mt < 2; ++mt) {
    int r = n0 + mt * 16 + c15;
    if (r > NPTS - 1) r = NPTS - 1;
#pragma unroll
    for (int ks = 0; ks < 2; ++ks) {
      const float* p = feats + (size_t)r * 64 + ks * 32 + g * 8;
      float4 u0 = *(const float4*)p, u1 = *(const float4*)(p + 4);
      a[mt][ks][0] = (_Float16)u0.x; a[mt][ks][1] = (_Float16)u0.y;
      a[mt][ks][2] = (_Float16)u0.z; a[mt][ks][3] = (_Float16)u0.w;
      a[mt][ks][4] = (_Float16)u1.x; a[mt][ks][5] = (_Float16)u1.y;
      a[mt][ks][6] = (_Float16)u1.z; a[mt][ks][7] = (_Float16)u1.w;
    }
  }
  floatx4 acc[2][4] = {};
#pragma unroll
  for (int ks = 0; ks < 2; ++ks)
#pragma unroll
    for (int nt = 0; nt < 4; ++nt) {
      half8 b = ldWtF32(Wq, c15, g, nt, ks);
#pragma unroll
      for (int mt = 0; mt < 2; ++mt)
        acc[mt][nt] = __builtin_amdgcn_mfma_f32_16x16x32_f16(a[mt][ks], b, acc[mt][nt], 0, 0, 0);
    }
#pragma unroll
  for (int nt = 0; nt < 4; ++nt) {
    float bqv = bq[nt * 16 + c15];
#pragma unroll
    for (int mt = 0; mt < 2; ++mt)
#pragma unroll
      for (int r = 0; r < 4; ++r) {
        int n = n0 + mt * 16 + g * 4 + r;
        if (n < NPTS)
          Qh[(size_t)n * 64 + nt * 16 + c15] = (_Float16)fmaxf(acc[mt][nt][r] + bqv, 0.f);
      }
  }
}

// ---------------------------------------------------------------------------
// Kernel A: fused per-point attention; one wave per point, MFMA matmuls.
// fc lives in LDS (T buffer) from birth; pe is never materialized (aP built
// in A-layout by fusing the fc transpose-read with coalesced feats loads);
// rel overwrites fc in place. Peak regs ~100 -> (256,4) without spills.
// ---------------------------------------------------------------------------
__global__ __launch_bounds__(256, 4) void attn_kernel(
    const float* __restrict__ coords, const float* __restrict__ feats,
    const float* __restrict__ bk, const float* __restrict__ bv,
    const float* __restrict__ Wl1, const float* __restrict__ bl1,
    const float* __restrict__ bl2, const float* __restrict__ bw1,
    const float* __restrict__ bw2, const float* __restrict__ g_att,
    const float* __restrict__ b_att, const int* __restrict__ knn,
    const _Float16* __restrict__ wtg, const _Float16* __restrict__ Qh,
    _Float16* __restrict__ h_out)
{
  __shared__ float Tsh[4][2048];
  const int wv = threadIdx.x >> 6, lane = threadIdx.x & 63;
  const int c15 = lane & 15, g = lane >> 4;
  const int n = blockIdx.x * 4 + wv;
  float* Tw = Tsh[wv];
  const int* row = knn + (size_t)n * 33;

  const _Float16* wt_l2 = wtg;
  const _Float16* wt_v  = wtg + 4096;
  const _Float16* wt_k  = wtg + 8192;
  const _Float16* wt_w1 = wtg + 12288;
  const _Float16* wt_w2 = wtg + 16384;

  // ---- h1 = relu(diff @ Wl1 + bl1), built directly in A-layout ----
  half8 aH[2][2];
  {
    float cnx = coords[(size_t)n * 3], cny = coords[(size_t)n * 3 + 1],
          cnz = coords[(size_t)n * 3 + 2];
#pragma unroll
    for (int ks = 0; ks < 2; ++ks) {
      int c0 = ks * 32 + g * 8;
      float4 wx0 = *(const float4*)(Wl1 + c0),       wx1 = *(const float4*)(Wl1 + c0 + 4);
      float4 wy0 = *(const float4*)(Wl1 + 64 + c0),  wy1 = *(const float4*)(Wl1 + 64 + c0 + 4);
      float4 wz0 = *(const float4*)(Wl1 + 128 + c0), wz1 = *(const float4*)(Wl1 + 128 + c0 + 4);
      float4 bb0 = *(const float4*)(bl1 + c0),       bb1 = *(const float4*)(bl1 + c0 + 4);
      float wx[8] = {wx0.x,wx0.y,wx0.z,wx0.w,wx1.x,wx1.y,wx1.z,wx1.w};
      float wy[8] = {wy0.x,wy0.y,wy0.z,wy0.w,wy1.x,wy1.y,wy1.z,wy1.w};
      float wz[8] = {wz0.x,wz0.y,wz0.z,wz0.w,wz1.x,wz1.y,wz1.z,wz1.w};
      float bb[8] = {bb0.x,bb0.y,bb0.z,bb0.w,bb1.x,bb1.y,bb1.z,bb1.w};
#pragma unroll
      for (int mt = 0; mt < 2; ++mt) {
        int id = row[mt * 16 + c15];
        float dx = coords[(size_t)id * 3] - cnx;
        float dy = coords[(size_t)id * 3 + 1] - cny;
        float dz = coords[(size_t)id * 3 + 2] - cnz;
#pragma unroll
        for (int j = 0; j < 8; ++j)
          aH[mt][ks][j] = (_Float16)fmaxf(dx * wx[j] + dy * wy[j] + dz * wz[j] + bb[j], 0.f);
      }
    }
  }

  // ---- fc = h1 @ Wl2 + bl2 -> straight to T (accs die here) ----
  {
    floatx4 fcacc[2][4] = {};
    domm(wt_l2, aH, c15, g, fcacc);
#pragma unroll
    for (int nt = 0; nt < 4; ++nt) {
      float b = bl2[nt * 16 + c15];
#pragma unroll
      for (int mt = 0; mt < 2; ++mt) stC(Tw, c15, g, mt, nt, fcacc[mt][nt] + b);
    }
  }
  __builtin_amdgcn_wave_barrier();

  // ---- aP = fp16(fc + feats[idx]) built directly in A-layout ----
  half8 aP[2][2];
#pragma unroll
  for (int mt = 0; mt < 2; ++mt) {
    int m = mt * 16 + c15;
    int rn = row[m];
#pragma unroll
    for (int ks = 0; ks < 2; ++ks) {
      const float* fp = feats + (size_t)rn * 64 + ks * 32 + g * 8;
      float4 u0 = *(const float4*)fp, u1 = *(const float4*)(fp + 4);
      float fv[8] = {u0.x,u0.y,u0.z,u0.w,u1.x,u1.y,u1.z,u1.w};
#pragma unroll
      for (int j = 0; j < 8; ++j) {
        int c = ks * 32 + g * 8 + j;              // c&7 == j
        float fcv = Tw[c * 32 + (((m >> 2) ^ j) << 2) + (m & 3)];
        aP[mt][ks][j] = (_Float16)(fcv + fv[j]);
      }
    }
  }
  __builtin_amdgcn_wave_barrier();

  // ---- KR = pe @ Wk ; rel = (relu(KR+bk) - Q) * fc, in place over fc ----
  {
    floatx4 KR[2][4] = {};
    domm(wt_k, aP, c15, g, KR);
    __builtin_amdgcn_wave_barrier();
#pragma unroll
    for (int nt = 0; nt < 4; ++nt) {
      float bkv = bk[nt * 16 + c15];
      float q4 = (float)Qh[(size_t)n * 64 + nt * 16 + c15];
#pragma unroll
      for (int mt = 0; mt < 2; ++mt) {
        floatx4 fcq = ldCread(Tw, c15, g, mt, nt);
        floatx4 v;
#pragma unroll
        for (int r = 0; r < 4; ++r)
          v[r] = (fmaxf(KR[mt][nt][r] + bkv, 0.f) - q4) * fcq[r];
        stC(Tw, c15, g, mt, nt, v);
      }
    }
  }
  __builtin_amdgcn_wave_barrier();
  half8 aR[2][2];
  ldAfrags(Tw, c15, g, aR);

  // ---- w1 = relu(rel @ Ww1 + bw1) -> T ----
  {
    floatx4 W1[2][4] = {};
    domm(wt_w1, aR, c15, g, W1);
    __builtin_amdgcn_wave_barrier();
#pragma unroll
    for (int nt = 0; nt < 4; ++nt) {
      float b = bw1[nt * 16 + c15];
#pragma unroll
      for (int mt = 0; mt < 2; ++mt) {
        floatx4 v;
#pragma unroll
        for (int r = 0; r < 4; ++r) v[r] = fmaxf(W1[mt][nt][r] + b, 0.f);
        stC(Tw, c15, g, mt, nt, v);
      }
    }
  }
  __builtin_amdgcn_wave_barrier();
  half8 aW[2][2];
  ldAfrags(Tw, c15, g, aW);

  // ---- w = w1 @ Ww2 + bw2 -> T ----
  {
    floatx4 WW[2][4] = {};
    domm(wt_w2, aW, c15, g, WW);
    __builtin_amdgcn_wave_barrier();
#pragma unroll
    for (int nt = 0; nt < 4; ++nt) {
      float b = bw2[nt * 16 + c15];
#pragma unroll
      for (int mt = 0; mt < 2; ++mt) stC(Tw, c15, g, mt, nt, WW[mt][nt] + b);
    }
  }
  __builtin_amdgcn_wave_barrier();

  // ---- sparsemax: lane d = lane sorts column d (from T) ----
  float tau;
  {
    float a[32];
#pragma unroll
    for (int i = 0; i < 8; ++i) {
      floatx4 ch = *(const floatx4*)(Tw + lane * 32 + ((i ^ (lane & 7)) << 2));
#pragma unroll
      for (int r = 0; r < 4; ++r) a[i * 4 + r] = ch[r];
    }
#pragma unroll
    for (int size = 2; size <= 32; size <<= 1) {
#pragma unroll
      for (int stride = size >> 1; stride > 0; stride >>= 1) {
#pragma unroll
        for (int i = 0; i < 32; ++i) {
          int j = i ^ stride;
          if (j > i) {
            float x = a[i], y = a[j];
            float lo = fminf(x, y), hi = fmaxf(x, y);
            bool up = ((i & size) == 0);
            a[i] = up ? hi : lo;
            a[j] = up ? lo : hi;
          }
        }
      }
    }
    float csum = 0.f, csel = 0.f;
    int ksup = 1;
#pragma unroll
    for (int i = 0; i < 32; ++i) {
      csum += a[i];
      if (1.0f + (float)(i + 1) * a[i] > csum) { ksup = i + 1; csel = csum; }
    }
    tau = (csel - 1.0f) / (float)ksup;
  }

  // ---- V = pe @ Wv + bv (aP still live; sort regs dead) ----
  floatx4 V[2][4] = {};
  domm(wt_v, aP, c15, g, V);
#pragma unroll
  for (int nt = 0; nt < 4; ++nt) {
    float b = bv[nt * 16 + c15];
#pragma unroll
    for (int mt = 0; mt < 2; ++mt) V[mt][nt] += b;
  }

  // ---- attn = sum_k max(w - tau, 0) * V ; x_att = 2*feats + attn; LN ----
  float x4[4];
#pragma unroll
  for (int nt = 0; nt < 4; ++nt) {
    float t4 = __shfl(tau, nt * 16 + c15, 64);
    float ssum = 0.f;
#pragma unroll
    for (int mt = 0; mt < 2; ++mt) {
      floatx4 w4 = ldCread(Tw, c15, g, mt, nt);
#pragma unroll
      for (int r = 0; r < 4; ++r)
        ssum += fmaxf(w4[r] - t4, 0.f) * V[mt][nt][r];
    }
    ssum += __shfl_xor(ssum, 16, 64);
    ssum += __shfl_xor(ssum, 32, 64);
    x4[nt] = 2.f * feats[(size_t)n * 64 + nt * 16 + c15] + ssum;
  }

  float sum = x4[0] + x4[1] + x4[2] + x4[3];
  float sum2 = x4[0] * x4[0] + x4[1] * x4[1] + x4[2] * x4[2] + x4[3] * x4[3];
#pragma unroll
  for (int m = 1; m < 16; m <<= 1) {
    sum += __shfl_xor(sum, m, 64);
    sum2 += __shfl_xor(sum2, m, 64);
  }
  float mean = sum * (1.f / 64.f);
  float var = sum2 * (1.f / 64.f) - mean * mean;
  float inv = rsqrtf(var + EPSF);
  h_out[(size_t)n * 64 + lane] =
      (_Float16)(g_att[lane] * (x4[g] - mean) * inv + b_att[lane]);
}

// ---------------------------------------------------------------------------
// Kernel B: graph conv + FFN + LN via MFMA. One wave = 16 points.
// ---------------------------------------------------------------------------
__global__ __launch_bounds__(256) void gconv_kernel(
    const float* __restrict__ coords, const _Float16* __restrict__ h,
    const _Float16* __restrict__ wtg, const float* __restrict__ Wsg,
    const float* __restrict__ bsg, const float* __restrict__ bf,
    const float* __restrict__ g_ff, const float* __restrict__ b_ff,
    const int* __restrict__ knn, float* __restrict__ out)
{
  __shared__ float Tsh[4][2048];
  const int wv = threadIdx.x >> 6, lane = threadIdx.x & 63;
  const int c15 = lane & 15, g = lane >> 4;
  const int n0 = (blockIdx.x * 4 + wv) * 16;
  if (n0 >= NPTS) return;
  float* Tw = Tsh[wv];
  const _Float16* wt_sg = wtg + 5 * 4096;
  const _Float16* wt_f  = wtg + 6 * 4096;
  const float inv33 = 1.0f / 33.0f;

  // ---- gather in A-layout: point p = n0 + c15, cols g*8.. and 32+g*8.. ----
  const int p = n0 + c15;
  const int* row = knn + (size_t)p * 33;
  float acc0[8] = {}, acc1[8] = {};
#pragma unroll 11
  for (int k = 0; k < 33; ++k) {
    int idx = (k == 0) ? p : row[k];
    const _Float16* hp = h + (size_t)idx * 64 + g * 8;
    half8 v0 = *(const half8*)hp;
    half8 v1 = *(const half8*)(hp + 32);
#pragma unroll
    for (int j = 0; j < 8; ++j) {
      acc0[j] += (float)v0[j];
      acc1[j] += (float)v1[j];
    }
  }
  float sx = 0.f, sy = 0.f, sz = 0.f;
  for (int k = g; k < 33; k += 4) {
    int idx = (k == 0) ? p : row[k];
    sx += coords[(size_t)idx * 3];
    sy += coords[(size_t)idx * 3 + 1];
    sz += coords[(size_t)idx * 3 + 2];
  }
  sx += __shfl_xor(sx, 16, 64); sx += __shfl_xor(sx, 32, 64);
  sy += __shfl_xor(sy, 16, 64); sy += __shfl_xor(sy, 32, 64);
  sz += __shfl_xor(sz, 16, 64); sz += __shfl_xor(sz, 32, 64);
  float cxa = sx * inv33, cya = sy * inv33, cza = sz * inv33;

  half8 aA[2];
#pragma unroll
  for (int j = 0; j < 8; ++j) {
    aA[0][j] = (_Float16)(acc0[j] * inv33);
    aA[1][j] = (_Float16)(acc1[j] * inv33);
  }

  // ---- t1 = relu(agg @ Wsg + coords-part + bsg) -> T (16-row half) ----
  {
    floatx4 C1[4] = {};
    domm1(wt_sg, aA, c15, g, C1);
#pragma unroll
    for (int nt = 0; nt < 4; ++nt) {
      int col = nt * 16 + c15;
      float b = bsg[col];
      float w64 = Wsg[4096 + col], w65 = Wsg[4160 + col], w66 = Wsg[4224 + col];
      floatx4 v;
#pragma unroll
      for (int r = 0; r < 4; ++r) {
        int src = g * 4 + r;
        float cx = __shfl(cxa, src, 64);
        float cy = __shfl(cya, src, 64);
        float cz = __shfl(cza, src, 64);
        v[r] = fmaxf(C1[nt][r] + b + cx * w64 + cy * w65 + cz * w66, 0.f);
      }
      stC(Tw, c15, g, 0, nt, v);
    }
  }
  __builtin_amdgcn_wave_barrier();
  half8 aT[2];
  aT[0] = ldA(Tw, c15, g, 0, 0);
  aT[1] = ldA(Tw, c15, g, 0, 1);

  // ---- x = t1 @ Wf + bf + h_self; LN over d; store ----
  floatx4 C2[4] = {};
  domm1(wt_f, aT, c15, g, C2);
#pragma unroll
  for (int nt = 0; nt < 4; ++nt) {
    float b = bf[nt * 16 + c15];
#pragma unroll
    for (int r = 0; r < 4; ++r)
      C2[nt][r] += b + (float)h[(size_t)(n0 + g * 4 + r) * 64 + nt * 16 + c15];
  }
#pragma unroll
  for (int r = 0; r < 4; ++r) {
    float s = C2[0][r] + C2[1][r] + C2[2][r] + C2[3][r];
    float s2 = C2[0][r] * C2[0][r] + C2[1][r] * C2[1][r] +
               C2[2][r] * C2[2][r] + C2[3][r] * C2[3][r];
#pragma unroll
    for (int m = 1; m < 16; m <<= 1) {
      s += __shfl_xor(s, m, 64);
      s2 += __shfl_xor(s2, m, 64);
    }
    float mean = s * (1.f / 64.f);
    float var = s2 * (1.f / 64.f) - mean * mean;
    float inv = rsqrtf(var + EPSF);
    int prow = n0 + g * 4 + r;
#pragma unroll
    for (int nt = 0; nt < 4; ++nt) {
      int col = nt * 16 + c15;
      out[(size_t)prow * 64 + col] =
          g_ff[col] * (C2[nt][r] - mean) * inv + b_ff[col];
    }
  }
}

extern "C" void kernel_launch(void* const* d_in, const int* in_sizes, int n_in,
                              void* d_out, int out_size, void* d_ws, size_t ws_size,
                              hipStream_t stream) {
  (void)in_sizes; (void)n_in; (void)out_size; (void)ws_size;
  const float* coords = (const float*)d_in[0];
  const float* feats  = (const float*)d_in[1];
  const float* Wq  = (const float*)d_in[2];  const float* bq  = (const float*)d_in[3];
  const float* Wk  = (const float*)d_in[4];  const float* bk  = (const float*)d_in[5];
  const float* Wv  = (const float*)d_in[6];  const float* bv  = (const float*)d_in[7];
  const float* Wl1 = (const float*)d_in[8];  const float* bl1 = (const float*)d_in[9];
  const float* Wl2 = (const float*)d_in[10]; const float* bl2 = (const float*)d_in[11];
  const float* Ww1 = (const float*)d_in[12]; const float* bw1 = (const float*)d_in[13];
  const float* Ww2 = (const float*)d_in[14]; const float* bw2 = (const float*)d_in[15];
  const float* g_att = (const float*)d_in[16]; const float* b_att = (const float*)d_in[17];
  const float* Wsg = (const float*)d_in[18]; const float* bsg = (const float*)d_in[19];
  const float* Wf  = (const float*)d_in[20]; const float* bf  = (const float*)d_in[21];
  const float* g_ff = (const float*)d_in[22]; const float* b_ff = (const float*)d_in[23];
  const int* knn = (const int*)d_in[24];

  // ws: [0, 2.56MB) h fp16 | [2.56MB, +56KB) swizzled weights | Qh fp16
  _Float16* h   = (_Float16*)d_ws;
  _Float16* wtg = (_Float16*)((char*)d_ws + 2621440);
  _Float16* Qh  = (_Float16*)((char*)d_ws + 2621440 + 57344);
  float* out = (float*)d_out;

  prep_q_kernel<<<dim3(164), dim3(256), 0, stream>>>(
      Wl2, Wv, Wk, Ww1, Ww2, Wsg, Wf, Wq, feats, bq, wtg, Qh);
  attn_kernel<<<dim3(NPTS / 4), dim3(256), 0, stream>>>(
      coords, feats, bk, bv, Wl1, bl1, bl2, bw1, bw2,
      g_att, b_att, knn, wtg, Qh, h);
  gconv_kernel<<<dim3(313), dim3(256), 0, stream>>>(
      coords, h, wtg, Wsg, bsg, bf, g_ff, b_ff, knn, out);
}

// Round 7
// 212.497 us; speedup vs baseline: 4.4728x; 1.0295x over previous
//
#include <hip/hip_runtime.h>

#define NPTS 20000
#define EPSF 1e-5f

typedef _Float16 half8 __attribute__((ext_vector_type(8)));
typedef float floatx4 __attribute__((ext_vector_type(4)));

// ---------------------------------------------------------------------------
// B-fragment: frag[j] = W[32ks+8g+j][16nt+c15], from swizzled fp16 weights:
//   [k][d] -> d*64 + (((k>>3)^(d&7))<<3) + (k&7)
// ---------------------------------------------------------------------------
__device__ __forceinline__ half8 ldWt(const _Float16* __restrict__ w,
                                      int c15, int g, int nt, int ks) {
  int c = nt * 16 + c15;
  int kg = ks * 4 + g;
  return *(const half8*)(w + c * 64 + ((kg ^ (c & 7)) << 3));
}

// B-fragment directly from fp32 row-major W (one-shot use, L2-hot)
__device__ __forceinline__ half8 ldWtF32(const float* __restrict__ W,
                                         int c15, int g, int nt, int ks) {
  int c = nt * 16 + c15;
  half8 r;
#pragma unroll
  for (int j = 0; j < 8; ++j) r[j] = (_Float16)W[(ks * 32 + g * 8 + j) * 64 + c];
  return r;
}

// Per-wave transpose buffer T: 64 cols x 32 rows fp32, XOR-swizzled chunks:
// [col][row] -> col*32 + (((row>>2)^(col&7))<<2) + (row&3)
__device__ __forceinline__ void stC(float* __restrict__ Tw, int c15, int g,
                                    int mt, int nt, floatx4 v) {
  int col = nt * 16 + c15;
  int chunk = mt * 4 + g;
  *(floatx4*)(Tw + col * 32 + ((chunk ^ (col & 7)) << 2)) = v;
}

__device__ __forceinline__ floatx4 ldCread(const float* __restrict__ Tw,
                                           int c15, int g, int mt, int nt) {
  int col = nt * 16 + c15;
  int chunk = mt * 4 + g;
  return *(const floatx4*)(Tw + col * 32 + ((chunk ^ (col & 7)) << 2));
}

// A-fragment from T: frag[j] = X[16mt+c15][32ks+8g+j] (fp32 -> fp16)
__device__ __forceinline__ half8 ldA(const float* __restrict__ Tw,
                                     int c15, int g, int mt, int ks) {
  int m = mt * 16 + c15;
  half8 r;
#pragma unroll
  for (int j = 0; j < 8; ++j) {
    int c = ks * 32 + g * 8 + j;                // c&7 == j
    r[j] = (_Float16)Tw[c * 32 + (((m >> 2) ^ j) << 2) + (m & 3)];
  }
  return r;
}

__device__ __forceinline__ void ldAfrags(const float* __restrict__ Tw,
                                         int c15, int g, half8 a[2][2]) {
#pragma unroll
  for (int mt = 0; mt < 2; ++mt)
#pragma unroll
    for (int ks = 0; ks < 2; ++ks) a[mt][ks] = ldA(Tw, c15, g, mt, ks);
}

__device__ __forceinline__ void domm(const _Float16* __restrict__ w,
                                     const half8 a[2][2], int c15, int g,
                                     floatx4 acc[2][4]) {
#pragma unroll
  for (int ks = 0; ks < 2; ++ks)
#pragma unroll
    for (int nt = 0; nt < 4; ++nt) {
      half8 b = ldWt(w, c15, g, nt, ks);
#pragma unroll
      for (int mt = 0; mt < 2; ++mt)
        acc[mt][nt] = __builtin_amdgcn_mfma_f32_16x16x32_f16(a[mt][ks], b, acc[mt][nt], 0, 0, 0);
    }
}

// single-mt (16-row) variant for gconv
__device__ __forceinline__ void domm1(const _Float16* __restrict__ w,
                                      const half8 a[2], int c15, int g,
                                      floatx4 acc[4]) {
#pragma unroll
  for (int ks = 0; ks < 2; ++ks)
#pragma unroll
    for (int nt = 0; nt < 4; ++nt) {
      half8 b = ldWt(w, c15, g, nt, ks);
      acc[nt] = __builtin_amdgcn_mfma_f32_16x16x32_f16(a[ks], b, acc[nt], 0, 0, 0);
    }
}

// ---------------------------------------------------------------------------
// Fused weight-prep (blocks 0..6) + Q precompute (blocks 7..163).
// prep order: Wl2, Wv, Wk, Ww1, Ww2, Wsg[0:64], Wf
// ---------------------------------------------------------------------------
__global__ __launch_bounds__(256) void prep_q_kernel(
    const float* __restrict__ Wl2, const float* __restrict__ Wv,
    const float* __restrict__ Wk, const float* __restrict__ Ww1,
    const float* __restrict__ Ww2, const float* __restrict__ Wsg,
    const float* __restrict__ Wf, const float* __restrict__ Wq,
    const float* __restrict__ feats, const float* __restrict__ bq,
    _Float16* __restrict__ wtg, _Float16* __restrict__ Qh)
{
  if (blockIdx.x < 7) {
    const float* srcs[7] = {Wl2, Wv, Wk, Ww1, Ww2, Wsg, Wf};
    const float* src = srcs[blockIdx.x];
    _Float16* dst = wtg + blockIdx.x * 4096;
    int t = threadIdx.x;
#pragma unroll
    for (int i = 0; i < 16; ++i) {
      int lin = i * 256 + t;            // = k*64 + d
      int k = lin >> 6, d = lin & 63;
      dst[d * 64 + (((k >> 3) ^ (d & 7)) << 3) + (k & 7)] = (_Float16)src[lin];
    }
    return;
  }
  // ---- Q = relu(feats @ Wq + bq), 32 points/wave ----
  const int wv = threadIdx.x >> 6, lane = threadIdx.x & 63;
  const int c15 = lane & 15, g = lane >> 4;
  const int n0 = ((blockIdx.x - 7) * 4 + wv) * 32;

  half8 a[2][2];
#pragma unroll
  for (int mt = 0; mt < 2; ++mt) {
    int r = n0 + mt * 16 + c15;
    if (r > NPTS - 1) r = NPTS - 1;
#pragma unroll
    for (int ks = 0; ks < 2; ++ks) {
      const float* p = feats + (size_t)r * 64 + ks * 32 + g * 8;
      float4 u0 = *(const float4*)p, u1 = *(const float4*)(p + 4);
      a[mt][ks][0] = (_Float16)u0.x; a[mt][ks][1] = (_Float16)u0.y;
      a[mt][ks][2] = (_Float16)u0.z; a[mt][ks][3] = (_Float16)u0.w;
      a[mt][ks][4] = (_Float16)u1.x; a[mt][ks][5] = (_Float16)u1.y;
      a[mt][ks][6] = (_Float16)u1.z; a[mt][ks][7] = (_Float16)u1.w;
    }
  }
  floatx4 acc[2][4] = {};
#pragma unroll
  for (int ks = 0; ks < 2; ++ks)
#pragma unroll
    for (int nt = 0; nt < 4; ++nt) {
      half8 b = ldWtF32(Wq, c15, g, nt, ks);
#pragma unroll
      for (int mt = 0; mt < 2; ++mt)
        acc[mt][nt] = __builtin_amdgcn_mfma_f32_16x16x32_f16(a[mt][ks], b, acc[mt][nt], 0, 0, 0);
    }
#pragma unroll
  for (int nt = 0; nt < 4; ++nt) {
    float bqv = bq[nt * 16 + c15];
#pragma unroll
    for (int mt = 0; mt < 2; ++mt)
#pragma unroll
      for (int r = 0; r < 4; ++r) {
        int n = n0 + mt * 16 + g * 4 + r;
        if (n < NPTS)
          Qh[(size_t)n * 64 + nt * 16 + c15] = (_Float16)fmaxf(acc[mt][nt][r] + bqv, 0.f);
      }
  }
}

// ---------------------------------------------------------------------------
// Kernel A: fused per-point attention (unchanged from R6; ~VALU-bound).
// ---------------------------------------------------------------------------
__global__ __launch_bounds__(256, 4) void attn_kernel(
    const float* __restrict__ coords, const float* __restrict__ feats,
    const float* __restrict__ bk, const float* __restrict__ bv,
    const float* __restrict__ Wl1, const float* __restrict__ bl1,
    const float* __restrict__ bl2, const float* __restrict__ bw1,
    const float* __restrict__ bw2, const float* __restrict__ g_att,
    const float* __restrict__ b_att, const int* __restrict__ knn,
    const _Float16* __restrict__ wtg, const _Float16* __restrict__ Qh,
    _Float16* __restrict__ h_out)
{
  __shared__ float Tsh[4][2048];
  const int wv = threadIdx.x >> 6, lane = threadIdx.x & 63;
  const int c15 = lane & 15, g = lane >> 4;
  const int n = blockIdx.x * 4 + wv;
  float* Tw = Tsh[wv];
  const int* row = knn + (size_t)n * 33;

  const _Float16* wt_l2 = wtg;
  const _Float16* wt_v  = wtg + 4096;
  const _Float16* wt_k  = wtg + 8192;
  const _Float16* wt_w1 = wtg + 12288;
  const _Float16* wt_w2 = wtg + 16384;

  // ---- h1 = relu(diff @ Wl1 + bl1), built directly in A-layout ----
  half8 aH[2][2];
  {
    float cnx = coords[(size_t)n * 3], cny = coords[(size_t)n * 3 + 1],
          cnz = coords[(size_t)n * 3 + 2];
#pragma unroll
    for (int ks = 0; ks < 2; ++ks) {
      int c0 = ks * 32 + g * 8;
      float4 wx0 = *(const float4*)(Wl1 + c0),       wx1 = *(const float4*)(Wl1 + c0 + 4);
      float4 wy0 = *(const float4*)(Wl1 + 64 + c0),  wy1 = *(const float4*)(Wl1 + 64 + c0 + 4);
      float4 wz0 = *(const float4*)(Wl1 + 128 + c0), wz1 = *(const float4*)(Wl1 + 128 + c0 + 4);
      float4 bb0 = *(const float4*)(bl1 + c0),       bb1 = *(const float4*)(bl1 + c0 + 4);
      float wx[8] = {wx0.x,wx0.y,wx0.z,wx0.w,wx1.x,wx1.y,wx1.z,wx1.w};
      float wy[8] = {wy0.x,wy0.y,wy0.z,wy0.w,wy1.x,wy1.y,wy1.z,wy1.w};
      float wz[8] = {wz0.x,wz0.y,wz0.z,wz0.w,wz1.x,wz1.y,wz1.z,wz1.w};
      float bb[8] = {bb0.x,bb0.y,bb0.z,bb0.w,bb1.x,bb1.y,bb1.z,bb1.w};
#pragma unroll
      for (int mt = 0; mt < 2; ++mt) {
        int id = row[mt * 16 + c15];
        float dx = coords[(size_t)id * 3] - cnx;
        float dy = coords[(size_t)id * 3 + 1] - cny;
        float dz = coords[(size_t)id * 3 + 2] - cnz;
#pragma unroll
        for (int j = 0; j < 8; ++j)
          aH[mt][ks][j] = (_Float16)fmaxf(dx * wx[j] + dy * wy[j] + dz * wz[j] + bb[j], 0.f);
      }
    }
  }

  // ---- fc = h1 @ Wl2 + bl2 -> straight to T (accs die here) ----
  {
    floatx4 fcacc[2][4] = {};
    domm(wt_l2, aH, c15, g, fcacc);
#pragma unroll
    for (int nt = 0; nt < 4; ++nt) {
      float b = bl2[nt * 16 + c15];
#pragma unroll
      for (int mt = 0; mt < 2; ++mt) stC(Tw, c15, g, mt, nt, fcacc[mt][nt] + b);
    }
  }
  __builtin_amdgcn_wave_barrier();

  // ---- aP = fp16(fc + feats[idx]) built directly in A-layout ----
  half8 aP[2][2];
#pragma unroll
  for (int mt = 0; mt < 2; ++mt) {
    int m = mt * 16 + c15;
    int rn = row[m];
#pragma unroll
    for (int ks = 0; ks < 2; ++ks) {
      const float* fp = feats + (size_t)rn * 64 + ks * 32 + g * 8;
      float4 u0 = *(const float4*)fp, u1 = *(const float4*)(fp + 4);
      float fv[8] = {u0.x,u0.y,u0.z,u0.w,u1.x,u1.y,u1.z,u1.w};
#pragma unroll
      for (int j = 0; j < 8; ++j) {
        int c = ks * 32 + g * 8 + j;              // c&7 == j
        float fcv = Tw[c * 32 + (((m >> 2) ^ j) << 2) + (m & 3)];
        aP[mt][ks][j] = (_Float16)(fcv + fv[j]);
      }
    }
  }
  __builtin_amdgcn_wave_barrier();

  // ---- KR = pe @ Wk ; rel = (relu(KR+bk) - Q) * fc, in place over fc ----
  {
    floatx4 KR[2][4] = {};
    domm(wt_k, aP, c15, g, KR);
    __builtin_amdgcn_wave_barrier();
#pragma unroll
    for (int nt = 0; nt < 4; ++nt) {
      float bkv = bk[nt * 16 + c15];
      float q4 = (float)Qh[(size_t)n * 64 + nt * 16 + c15];
#pragma unroll
      for (int mt = 0; mt < 2; ++mt) {
        floatx4 fcq = ldCread(Tw, c15, g, mt, nt);
        floatx4 v;
#pragma unroll
        for (int r = 0; r < 4; ++r)
          v[r] = (fmaxf(KR[mt][nt][r] + bkv, 0.f) - q4) * fcq[r];
        stC(Tw, c15, g, mt, nt, v);
      }
    }
  }
  __builtin_amdgcn_wave_barrier();
  half8 aR[2][2];
  ldAfrags(Tw, c15, g, aR);

  // ---- w1 = relu(rel @ Ww1 + bw1) -> T ----
  {
    floatx4 W1[2][4] = {};
    domm(wt_w1, aR, c15, g, W1);
    __builtin_amdgcn_wave_barrier();
#pragma unroll
    for (int nt = 0; nt < 4; ++nt) {
      float b = bw1[nt * 16 + c15];
#pragma unroll
      for (int mt = 0; mt < 2; ++mt) {
        floatx4 v;
#pragma unroll
        for (int r = 0; r < 4; ++r) v[r] = fmaxf(W1[mt][nt][r] + b, 0.f);
        stC(Tw, c15, g, mt, nt, v);
      }
    }
  }
  __builtin_amdgcn_wave_barrier();
  half8 aW[2][2];
  ldAfrags(Tw, c15, g, aW);

  // ---- w = w1 @ Ww2 + bw2 -> T ----
  {
    floatx4 WW[2][4] = {};
    domm(wt_w2, aW, c15, g, WW);
    __builtin_amdgcn_wave_barrier();
#pragma unroll
    for (int nt = 0; nt < 4; ++nt) {
      float b = bw2[nt * 16 + c15];
#pragma unroll
      for (int mt = 0; mt < 2; ++mt) stC(Tw, c15, g, mt, nt, WW[mt][nt] + b);
    }
  }
  __builtin_amdgcn_wave_barrier();

  // ---- sparsemax: lane d = lane sorts column d (from T) ----
  float tau;
  {
    float a[32];
#pragma unroll
    for (int i = 0; i < 8; ++i) {
      floatx4 ch = *(const floatx4*)(Tw + lane * 32 + ((i ^ (lane & 7)) << 2));
#pragma unroll
      for (int r = 0; r < 4; ++r) a[i * 4 + r] = ch[r];
    }
#pragma unroll
    for (int size = 2; size <= 32; size <<= 1) {
#pragma unroll
      for (int stride = size >> 1; stride > 0; stride >>= 1) {
#pragma unroll
        for (int i = 0; i < 32; ++i) {
          int j = i ^ stride;
          if (j > i) {
            float x = a[i], y = a[j];
            float lo = fminf(x, y), hi = fmaxf(x, y);
            bool up = ((i & size) == 0);
            a[i] = up ? hi : lo;
            a[j] = up ? lo : hi;
          }
        }
      }
    }
    float csum = 0.f, csel = 0.f;
    int ksup = 1;
#pragma unroll
    for (int i = 0; i < 32; ++i) {
      csum += a[i];
      if (1.0f + (float)(i + 1) * a[i] > csum) { ksup = i + 1; csel = csum; }
    }
    tau = (csel - 1.0f) / (float)ksup;
  }

  // ---- V = pe @ Wv + bv (aP still live; sort regs dead) ----
  floatx4 V[2][4] = {};
  domm(wt_v, aP, c15, g, V);
#pragma unroll
  for (int nt = 0; nt < 4; ++nt) {
    float b = bv[nt * 16 + c15];
#pragma unroll
    for (int mt = 0; mt < 2; ++mt) V[mt][nt] += b;
  }

  // ---- attn = sum_k max(w - tau, 0) * V ; x_att = 2*feats + attn; LN ----
  float x4[4];
#pragma unroll
  for (int nt = 0; nt < 4; ++nt) {
    float t4 = __shfl(tau, nt * 16 + c15, 64);
    float ssum = 0.f;
#pragma unroll
    for (int mt = 0; mt < 2; ++mt) {
      floatx4 w4 = ldCread(Tw, c15, g, mt, nt);
#pragma unroll
      for (int r = 0; r < 4; ++r)
        ssum += fmaxf(w4[r] - t4, 0.f) * V[mt][nt][r];
    }
    ssum += __shfl_xor(ssum, 16, 64);
    ssum += __shfl_xor(ssum, 32, 64);
    x4[nt] = 2.f * feats[(size_t)n * 64 + nt * 16 + c15] + ssum;
  }

  float sum = x4[0] + x4[1] + x4[2] + x4[3];
  float sum2 = x4[0] * x4[0] + x4[1] * x4[1] + x4[2] * x4[2] + x4[3] * x4[3];
#pragma unroll
  for (int m = 1; m < 16; m <<= 1) {
    sum += __shfl_xor(sum, m, 64);
    sum2 += __shfl_xor(sum2, m, 64);
  }
  float mean = sum * (1.f / 64.f);
  float var = sum2 * (1.f / 64.f) - mean * mean;
  float inv = rsqrtf(var + EPSF);
  h_out[(size_t)n * 64 + lane] =
      (_Float16)(g_att[lane] * (x4[g] - mean) * inv + b_att[lane]);
}

// ---------------------------------------------------------------------------
// Kernel B v3: graph conv + FFN + LN. Block = 16 points.
// Phase 1 (4 waves): row-COALESCED gather (lane = dim, one 128B h-row per
// load instr; neighbor indices broadcast via shfl) -> padded LDS tile.
// Phase 2 (wave 0): MFMA t1/x GEMMs + coords term + residual + LN + store.
// ---------------------------------------------------------------------------
__global__ __launch_bounds__(256) void gconv_kernel(
    const float* __restrict__ coords, const _Float16* __restrict__ h,
    const _Float16* __restrict__ wtg, const float* __restrict__ Wsg,
    const float* __restrict__ bsg, const float* __restrict__ bf,
    const float* __restrict__ g_ff, const float* __restrict__ b_ff,
    const int* __restrict__ knn, float* __restrict__ out)
{
  __shared__ float agg_s[16 * 68];      // padded rows: <=2-way banks
  __shared__ float cm_s[16 * 4];
  __shared__ float T2[2048];
  const int wv = threadIdx.x >> 6, lane = threadIdx.x & 63;
  const int c15 = lane & 15, g = lane >> 4;
  const int n0 = blockIdx.x * 16;
  const float inv33 = 1.0f / 33.0f;
  const _Float16* wt_sg = wtg + 5 * 4096;
  const _Float16* wt_f  = wtg + 6 * 4096;

  // ---- phase 1: gather, 4 points per wave ----
#pragma unroll
  for (int i = 0; i < 4; ++i) {
    int pl = wv * 4 + i;
    int p = n0 + pl;
    int idxv = 0;
    if (lane < 33) idxv = knn[(size_t)p * 33 + lane];
    float acc = (float)h[(size_t)p * 64 + lane];          // self loop
#pragma unroll 8
    for (int k = 1; k <= 32; ++k) {
      int idx = __shfl(idxv, k, 64);
      acc += (float)h[(size_t)idx * 64 + lane];           // coalesced 128B row
    }
    agg_s[pl * 68 + lane] = acc * inv33;
    float sx = 0.f, sy = 0.f, sz = 0.f;
    if (lane < 33) {
      int src = (lane == 0) ? p : idxv;
      sx = coords[(size_t)src * 3];
      sy = coords[(size_t)src * 3 + 1];
      sz = coords[(size_t)src * 3 + 2];
    }
#pragma unroll
    for (int m = 1; m < 64; m <<= 1) {
      sx += __shfl_xor(sx, m, 64);
      sy += __shfl_xor(sy, m, 64);
      sz += __shfl_xor(sz, m, 64);
    }
    if (lane == 0) {
      cm_s[pl * 4 + 0] = sx * inv33;
      cm_s[pl * 4 + 1] = sy * inv33;
      cm_s[pl * 4 + 2] = sz * inv33;
    }
  }
  __syncthreads();
  if (wv != 0) return;

  // ---- phase 2 (wave 0): A-frags from agg tile (row m = point c15) ----
  half8 aA[2];
#pragma unroll
  for (int ks = 0; ks < 2; ++ks) {
    const float* pr = agg_s + c15 * 68 + ks * 32 + g * 8;
    float4 u0 = *(const float4*)pr, u1 = *(const float4*)(pr + 4);
    aA[ks][0] = (_Float16)u0.x; aA[ks][1] = (_Float16)u0.y;
    aA[ks][2] = (_Float16)u0.z; aA[ks][3] = (_Float16)u0.w;
    aA[ks][4] = (_Float16)u1.x; aA[ks][5] = (_Float16)u1.y;
    aA[ks][6] = (_Float16)u1.z; aA[ks][7] = (_Float16)u1.w;
  }

  // coords means for this lane's 4 C-rows (pl = 4g + r)
  float cmx[4], cmy[4], cmz[4];
#pragma unroll
  for (int r = 0; r < 4; ++r) {
    int pl = g * 4 + r;
    cmx[r] = cm_s[pl * 4 + 0];
    cmy[r] = cm_s[pl * 4 + 1];
    cmz[r] = cm_s[pl * 4 + 2];
  }

  // ---- t1 = relu(agg @ Wsg + coords-part + bsg) -> T2 ----
  {
    floatx4 C1[4] = {};
    domm1(wt_sg, aA, c15, g, C1);
#pragma unroll
    for (int nt = 0; nt < 4; ++nt) {
      int col = nt * 16 + c15;
      float b = bsg[col];
      float w64 = Wsg[4096 + col], w65 = Wsg[4160 + col], w66 = Wsg[4224 + col];
      floatx4 v;
#pragma unroll
      for (int r = 0; r < 4; ++r)
        v[r] = fmaxf(C1[nt][r] + b + cmx[r] * w64 + cmy[r] * w65 + cmz[r] * w66, 0.f);
      stC(T2, c15, g, 0, nt, v);
    }
  }
  __builtin_amdgcn_wave_barrier();
  half8 aT[2];
  aT[0] = ldA(T2, c15, g, 0, 0);
  aT[1] = ldA(T2, c15, g, 0, 1);

  // ---- x = t1 @ Wf + bf + h_self; LN over d; store ----
  floatx4 C2[4] = {};
  domm1(wt_f, aT, c15, g, C2);
#pragma unroll
  for (int nt = 0; nt < 4; ++nt) {
    int col = nt * 16 + c15;
    float b = bf[col];
#pragma unroll
    for (int r = 0; r < 4; ++r)
      C2[nt][r] += b + (float)h[(size_t)(n0 + g * 4 + r) * 64 + col];
  }
#pragma unroll
  for (int r = 0; r < 4; ++r) {
    float s = C2[0][r] + C2[1][r] + C2[2][r] + C2[3][r];
    float s2 = C2[0][r] * C2[0][r] + C2[1][r] * C2[1][r] +
               C2[2][r] * C2[2][r] + C2[3][r] * C2[3][r];
#pragma unroll
    for (int m = 1; m < 16; m <<= 1) {
      s += __shfl_xor(s, m, 64);
      s2 += __shfl_xor(s2, m, 64);
    }
    float mean = s * (1.f / 64.f);
    float var = s2 * (1.f / 64.f) - mean * mean;
    float inv = rsqrtf(var + EPSF);
    int prow = n0 + g * 4 + r;
#pragma unroll
    for (int nt = 0; nt < 4; ++nt) {
      int col = nt * 16 + c15;
      out[(size_t)prow * 64 + col] =
          g_ff[col] * (C2[nt][r] - mean) * inv + b_ff[col];
    }
  }
}

extern "C" void kernel_launch(void* const* d_in, const int* in_sizes, int n_in,
                              void* d_out, int out_size, void* d_ws, size_t ws_size,
                              hipStream_t stream) {
  (void)in_sizes; (void)n_in; (void)out_size; (void)ws_size;
  const float* coords = (const float*)d_in[0];
  const float* feats  = (const float*)d_in[1];
  const float* Wq  = (const float*)d_in[2];  const float* bq  = (const float*)d_in[3];
  const float* Wk  = (const float*)d_in[4];  const float* bk  = (const float*)d_in[5];
  const float* Wv  = (const float*)d_in[6];  const float* bv  = (const float*)d_in[7];
  const float* Wl1 = (const float*)d_in[8];  const float* bl1 = (const float*)d_in[9];
  const float* Wl2 = (const float*)d_in[10]; const float* bl2 = (const float*)d_in[11];
  const float* Ww1 = (const float*)d_in[12]; const float* bw1 = (const float*)d_in[13];
  const float* Ww2 = (const float*)d_in[14]; const float* bw2 = (const float*)d_in[15];
  const float* g_att = (const float*)d_in[16]; const float* b_att = (const float*)d_in[17];
  const float* Wsg = (const float*)d_in[18]; const float* bsg = (const float*)d_in[19];
  const float* Wf  = (const float*)d_in[20]; const float* bf  = (const float*)d_in[21];
  const float* g_ff = (const float*)d_in[22]; const float* b_ff = (const float*)d_in[23];
  const int* knn = (const int*)d_in[24];

  // ws: [0, 2.56MB) h fp16 | [2.56MB, +56KB) swizzled weights | Qh fp16
  _Float16* h   = (_Float16*)d_ws;
  _Float16* wtg = (_Float16*)((char*)d_ws + 2621440);
  _Float16* Qh  = (_Float16*)((char*)d_ws + 2621440 + 57344);
  float* out = (float*)d_out;

  prep_q_kernel<<<dim3(164), dim3(256), 0, stream>>>(
      Wl2, Wv, Wk, Ww1, Ww2, Wsg, Wf, Wq, feats, bq, wtg, Qh);
  attn_kernel<<<dim3(NPTS / 4), dim3(256), 0, stream>>>(
      coords, feats, bk, bv, Wl1, bl1, bl2, bw1, bw2,
      g_att, b_att, knn, wtg, Qh, h);
  gconv_kernel<<<dim3(NPTS / 16), dim3(256), 0, stream>>>(
      coords, h, wtg, Wsg, bsg, bf, g_ff, b_ff, knn, out);
}

// Round 8
// 210.315 us; speedup vs baseline: 4.5193x; 1.0104x over previous
//
#include <hip/hip_runtime.h>

#define NPTS 20000
#define EPSF 1e-5f

typedef _Float16 half8 __attribute__((ext_vector_type(8)));
typedef float floatx4 __attribute__((ext_vector_type(4)));

// ---------------------------------------------------------------------------
// B-fragment: frag[j] = W[32ks+8g+j][16nt+c15], from swizzled fp16 weights:
//   [k][d] -> d*64 + (((k>>3)^(d&7))<<3) + (k&7)
// ---------------------------------------------------------------------------
__device__ __forceinline__ half8 ldWt(const _Float16* __restrict__ w,
                                      int c15, int g, int nt, int ks) {
  int c = nt * 16 + c15;
  int kg = ks * 4 + g;
  return *(const half8*)(w + c * 64 + ((kg ^ (c & 7)) << 3));
}

// B-fragment directly from fp32 row-major W (one-shot use, L2-hot)
__device__ __forceinline__ half8 ldWtF32(const float* __restrict__ W,
                                         int c15, int g, int nt, int ks) {
  int c = nt * 16 + c15;
  half8 r;
#pragma unroll
  for (int j = 0; j < 8; ++j) r[j] = (_Float16)W[(ks * 32 + g * 8 + j) * 64 + c];
  return r;
}

// Per-wave transpose buffer T: 64 cols x 32 rows fp32, XOR-swizzled chunks:
// [col][row] -> col*32 + (((row>>2)^(col&7))<<2) + (row&3)
__device__ __forceinline__ void stC(float* __restrict__ Tw, int c15, int g,
                                    int mt, int nt, floatx4 v) {
  int col = nt * 16 + c15;
  int chunk = mt * 4 + g;
  *(floatx4*)(Tw + col * 32 + ((chunk ^ (col & 7)) << 2)) = v;
}

__device__ __forceinline__ floatx4 ldCread(const float* __restrict__ Tw,
                                           int c15, int g, int mt, int nt) {
  int col = nt * 16 + c15;
  int chunk = mt * 4 + g;
  return *(const floatx4*)(Tw + col * 32 + ((chunk ^ (col & 7)) << 2));
}

// A-fragment from T: frag[j] = X[16mt+c15][32ks+8g+j] (fp32 -> fp16)
__device__ __forceinline__ half8 ldA(const float* __restrict__ Tw,
                                     int c15, int g, int mt, int ks) {
  int m = mt * 16 + c15;
  half8 r;
#pragma unroll
  for (int j = 0; j < 8; ++j) {
    int c = ks * 32 + g * 8 + j;                // c&7 == j
    r[j] = (_Float16)Tw[c * 32 + (((m >> 2) ^ j) << 2) + (m & 3)];
  }
  return r;
}

__device__ __forceinline__ void ldAfrags(const float* __restrict__ Tw,
                                         int c15, int g, half8 a[2][2]) {
#pragma unroll
  for (int mt = 0; mt < 2; ++mt)
#pragma unroll
    for (int ks = 0; ks < 2; ++ks) a[mt][ks] = ldA(Tw, c15, g, mt, ks);
}

__device__ __forceinline__ void domm(const _Float16* __restrict__ w,
                                     const half8 a[2][2], int c15, int g,
                                     floatx4 acc[2][4]) {
#pragma unroll
  for (int ks = 0; ks < 2; ++ks)
#pragma unroll
    for (int nt = 0; nt < 4; ++nt) {
      half8 b = ldWt(w, c15, g, nt, ks);
#pragma unroll
      for (int mt = 0; mt < 2; ++mt)
        acc[mt][nt] = __builtin_amdgcn_mfma_f32_16x16x32_f16(a[mt][ks], b, acc[mt][nt], 0, 0, 0);
    }
}

// single-mt (16-row) variant for gconv
__device__ __forceinline__ void domm1(const _Float16* __restrict__ w,
                                      const half8 a[2], int c15, int g,
                                      floatx4 acc[4]) {
#pragma unroll
  for (int ks = 0; ks < 2; ++ks)
#pragma unroll
    for (int nt = 0; nt < 4; ++nt) {
      half8 b = ldWt(w, c15, g, nt, ks);
      acc[nt] = __builtin_amdgcn_mfma_f32_16x16x32_f16(a[ks], b, acc[nt], 0, 0, 0);
    }
}

// ---------------------------------------------------------------------------
// Fused weight-prep (blocks 0..6) + Q precompute (blocks 7..163).
// prep order: Wl2, Wv, Wk, Ww1, Ww2, Wsg[0:64], Wf
// ---------------------------------------------------------------------------
__global__ __launch_bounds__(256) void prep_q_kernel(
    const float* __restrict__ Wl2, const float* __restrict__ Wv,
    const float* __restrict__ Wk, const float* __restrict__ Ww1,
    const float* __restrict__ Ww2, const float* __restrict__ Wsg,
    const float* __restrict__ Wf, const float* __restrict__ Wq,
    const float* __restrict__ feats, const float* __restrict__ bq,
    _Float16* __restrict__ wtg, _Float16* __restrict__ Qh)
{
  if (blockIdx.x < 7) {
    const float* srcs[7] = {Wl2, Wv, Wk, Ww1, Ww2, Wsg, Wf};
    const float* src = srcs[blockIdx.x];
    _Float16* dst = wtg + blockIdx.x * 4096;
    int t = threadIdx.x;
#pragma unroll
    for (int i = 0; i < 16; ++i) {
      int lin = i * 256 + t;            // = k*64 + d
      int k = lin >> 6, d = lin & 63;
      dst[d * 64 + (((k >> 3) ^ (d & 7)) << 3) + (k & 7)] = (_Float16)src[lin];
    }
    return;
  }
  // ---- Q = relu(feats @ Wq + bq), 32 points/wave ----
  const int wv = threadIdx.x >> 6, lane = threadIdx.x & 63;
  const int c15 = lane & 15, g = lane >> 4;
  const int n0 = ((blockIdx.x - 7) * 4 + wv) * 32;

  half8 a[2][2];
#pragma unroll
  for (int mt = 0; mt < 2; ++mt) {
    int r = n0 + mt * 16 + c15;
    if (r > NPTS - 1) r = NPTS - 1;
#pragma unroll
    for (int ks = 0; ks < 2; ++ks) {
      const float* p = feats + (size_t)r * 64 + ks * 32 + g * 8;
      float4 u0 = *(const float4*)p, u1 = *(const float4*)(p + 4);
      a[mt][ks][0] = (_Float16)u0.x; a[mt][ks][1] = (_Float16)u0.y;
      a[mt][ks][2] = (_Float16)u0.z; a[mt][ks][3] = (_Float16)u0.w;
      a[mt][ks][4] = (_Float16)u1.x; a[mt][ks][5] = (_Float16)u1.y;
      a[mt][ks][6] = (_Float16)u1.z; a[mt][ks][7] = (_Float16)u1.w;
    }
  }
  floatx4 acc[2][4] = {};
#pragma unroll
  for (int ks = 0; ks < 2; ++ks)
#pragma unroll
    for (int nt = 0; nt < 4; ++nt) {
      half8 b = ldWtF32(Wq, c15, g, nt, ks);
#pragma unroll
      for (int mt = 0; mt < 2; ++mt)
        acc[mt][nt] = __builtin_amdgcn_mfma_f32_16x16x32_f16(a[mt][ks], b, acc[mt][nt], 0, 0, 0);
    }
#pragma unroll
  for (int nt = 0; nt < 4; ++nt) {
    float bqv = bq[nt * 16 + c15];
#pragma unroll
    for (int mt = 0; mt < 2; ++mt)
#pragma unroll
      for (int r = 0; r < 4; ++r) {
        int n = n0 + mt * 16 + g * 4 + r;
        if (n < NPTS)
          Qh[(size_t)n * 64 + nt * 16 + c15] = (_Float16)fmaxf(acc[mt][nt][r] + bqv, 0.f);
      }
  }
}

// ---------------------------------------------------------------------------
// Kernel A: fused per-point attention (unchanged from R7).
// ---------------------------------------------------------------------------
__global__ __launch_bounds__(256, 4) void attn_kernel(
    const float* __restrict__ coords, const float* __restrict__ feats,
    const float* __restrict__ bk, const float* __restrict__ bv,
    const float* __restrict__ Wl1, const float* __restrict__ bl1,
    const float* __restrict__ bl2, const float* __restrict__ bw1,
    const float* __restrict__ bw2, const float* __restrict__ g_att,
    const float* __restrict__ b_att, const int* __restrict__ knn,
    const _Float16* __restrict__ wtg, const _Float16* __restrict__ Qh,
    _Float16* __restrict__ h_out)
{
  __shared__ float Tsh[4][2048];
  const int wv = threadIdx.x >> 6, lane = threadIdx.x & 63;
  const int c15 = lane & 15, g = lane >> 4;
  const int n = blockIdx.x * 4 + wv;
  float* Tw = Tsh[wv];
  const int* row = knn + (size_t)n * 33;

  const _Float16* wt_l2 = wtg;
  const _Float16* wt_v  = wtg + 4096;
  const _Float16* wt_k  = wtg + 8192;
  const _Float16* wt_w1 = wtg + 12288;
  const _Float16* wt_w2 = wtg + 16384;

  // ---- h1 = relu(diff @ Wl1 + bl1), built directly in A-layout ----
  half8 aH[2][2];
  {
    float cnx = coords[(size_t)n * 3], cny = coords[(size_t)n * 3 + 1],
          cnz = coords[(size_t)n * 3 + 2];
#pragma unroll
    for (int ks = 0; ks < 2; ++ks) {
      int c0 = ks * 32 + g * 8;
      float4 wx0 = *(const float4*)(Wl1 + c0),       wx1 = *(const float4*)(Wl1 + c0 + 4);
      float4 wy0 = *(const float4*)(Wl1 + 64 + c0),  wy1 = *(const float4*)(Wl1 + 64 + c0 + 4);
      float4 wz0 = *(const float4*)(Wl1 + 128 + c0), wz1 = *(const float4*)(Wl1 + 128 + c0 + 4);
      float4 bb0 = *(const float4*)(bl1 + c0),       bb1 = *(const float4*)(bl1 + c0 + 4);
      float wx[8] = {wx0.x,wx0.y,wx0.z,wx0.w,wx1.x,wx1.y,wx1.z,wx1.w};
      float wy[8] = {wy0.x,wy0.y,wy0.z,wy0.w,wy1.x,wy1.y,wy1.z,wy1.w};
      float wz[8] = {wz0.x,wz0.y,wz0.z,wz0.w,wz1.x,wz1.y,wz1.z,wz1.w};
      float bb[8] = {bb0.x,bb0.y,bb0.z,bb0.w,bb1.x,bb1.y,bb1.z,bb1.w};
#pragma unroll
      for (int mt = 0; mt < 2; ++mt) {
        int id = row[mt * 16 + c15];
        float dx = coords[(size_t)id * 3] - cnx;
        float dy = coords[(size_t)id * 3 + 1] - cny;
        float dz = coords[(size_t)id * 3 + 2] - cnz;
#pragma unroll
        for (int j = 0; j < 8; ++j)
          aH[mt][ks][j] = (_Float16)fmaxf(dx * wx[j] + dy * wy[j] + dz * wz[j] + bb[j], 0.f);
      }
    }
  }

  // ---- fc = h1 @ Wl2 + bl2 -> straight to T (accs die here) ----
  {
    floatx4 fcacc[2][4] = {};
    domm(wt_l2, aH, c15, g, fcacc);
#pragma unroll
    for (int nt = 0; nt < 4; ++nt) {
      float b = bl2[nt * 16 + c15];
#pragma unroll
      for (int mt = 0; mt < 2; ++mt) stC(Tw, c15, g, mt, nt, fcacc[mt][nt] + b);
    }
  }
  __builtin_amdgcn_wave_barrier();

  // ---- aP = fp16(fc + feats[idx]) built directly in A-layout ----
  half8 aP[2][2];
#pragma unroll
  for (int mt = 0; mt < 2; ++mt) {
    int m = mt * 16 + c15;
    int rn = row[m];
#pragma unroll
    for (int ks = 0; ks < 2; ++ks) {
      const float* fp = feats + (size_t)rn * 64 + ks * 32 + g * 8;
      float4 u0 = *(const float4*)fp, u1 = *(const float4*)(fp + 4);
      float fv[8] = {u0.x,u0.y,u0.z,u0.w,u1.x,u1.y,u1.z,u1.w};
#pragma unroll
      for (int j = 0; j < 8; ++j) {
        int c = ks * 32 + g * 8 + j;              // c&7 == j
        float fcv = Tw[c * 32 + (((m >> 2) ^ j) << 2) + (m & 3)];
        aP[mt][ks][j] = (_Float16)(fcv + fv[j]);
      }
    }
  }
  __builtin_amdgcn_wave_barrier();

  // ---- KR = pe @ Wk ; rel = (relu(KR+bk) - Q) * fc, in place over fc ----
  {
    floatx4 KR[2][4] = {};
    domm(wt_k, aP, c15, g, KR);
    __builtin_amdgcn_wave_barrier();
#pragma unroll
    for (int nt = 0; nt < 4; ++nt) {
      float bkv = bk[nt * 16 + c15];
      float q4 = (float)Qh[(size_t)n * 64 + nt * 16 + c15];
#pragma unroll
      for (int mt = 0; mt < 2; ++mt) {
        floatx4 fcq = ldCread(Tw, c15, g, mt, nt);
        floatx4 v;
#pragma unroll
        for (int r = 0; r < 4; ++r)
          v[r] = (fmaxf(KR[mt][nt][r] + bkv, 0.f) - q4) * fcq[r];
        stC(Tw, c15, g, mt, nt, v);
      }
    }
  }
  __builtin_amdgcn_wave_barrier();
  half8 aR[2][2];
  ldAfrags(Tw, c15, g, aR);

  // ---- w1 = relu(rel @ Ww1 + bw1) -> T ----
  {
    floatx4 W1[2][4] = {};
    domm(wt_w1, aR, c15, g, W1);
    __builtin_amdgcn_wave_barrier();
#pragma unroll
    for (int nt = 0; nt < 4; ++nt) {
      float b = bw1[nt * 16 + c15];
#pragma unroll
      for (int mt = 0; mt < 2; ++mt) {
        floatx4 v;
#pragma unroll
        for (int r = 0; r < 4; ++r) v[r] = fmaxf(W1[mt][nt][r] + b, 0.f);
        stC(Tw, c15, g, mt, nt, v);
      }
    }
  }
  __builtin_amdgcn_wave_barrier();
  half8 aW[2][2];
  ldAfrags(Tw, c15, g, aW);

  // ---- w = w1 @ Ww2 + bw2 -> T ----
  {
    floatx4 WW[2][4] = {};
    domm(wt_w2, aW, c15, g, WW);
    __builtin_amdgcn_wave_barrier();
#pragma unroll
    for (int nt = 0; nt < 4; ++nt) {
      float b = bw2[nt * 16 + c15];
#pragma unroll
      for (int mt = 0; mt < 2; ++mt) stC(Tw, c15, g, mt, nt, WW[mt][nt] + b);
    }
  }
  __builtin_amdgcn_wave_barrier();

  // ---- sparsemax: lane d = lane sorts column d (from T) ----
  float tau;
  {
    float a[32];
#pragma unroll
    for (int i = 0; i < 8; ++i) {
      floatx4 ch = *(const floatx4*)(Tw + lane * 32 + ((i ^ (lane & 7)) << 2));
#pragma unroll
      for (int r = 0; r < 4; ++r) a[i * 4 + r] = ch[r];
    }
#pragma unroll
    for (int size = 2; size <= 32; size <<= 1) {
#pragma unroll
      for (int stride = size >> 1; stride > 0; stride >>= 1) {
#pragma unroll
        for (int i = 0; i < 32; ++i) {
          int j = i ^ stride;
          if (j > i) {
            float x = a[i], y = a[j];
            float lo = fminf(x, y), hi = fmaxf(x, y);
            bool up = ((i & size) == 0);
            a[i] = up ? hi : lo;
            a[j] = up ? lo : hi;
          }
        }
      }
    }
    float csum = 0.f, csel = 0.f;
    int ksup = 1;
#pragma unroll
    for (int i = 0; i < 32; ++i) {
      csum += a[i];
      if (1.0f + (float)(i + 1) * a[i] > csum) { ksup = i + 1; csel = csum; }
    }
    tau = (csel - 1.0f) / (float)ksup;
  }

  // ---- V = pe @ Wv + bv (aP still live; sort regs dead) ----
  floatx4 V[2][4] = {};
  domm(wt_v, aP, c15, g, V);
#pragma unroll
  for (int nt = 0; nt < 4; ++nt) {
    float b = bv[nt * 16 + c15];
#pragma unroll
    for (int mt = 0; mt < 2; ++mt) V[mt][nt] += b;
  }

  // ---- attn = sum_k max(w - tau, 0) * V ; x_att = 2*feats + attn; LN ----
  float x4[4];
#pragma unroll
  for (int nt = 0; nt < 4; ++nt) {
    float t4 = __shfl(tau, nt * 16 + c15, 64);
    float ssum = 0.f;
#pragma unroll
    for (int mt = 0; mt < 2; ++mt) {
      floatx4 w4 = ldCread(Tw, c15, g, mt, nt);
#pragma unroll
      for (int r = 0; r < 4; ++r)
        ssum += fmaxf(w4[r] - t4, 0.f) * V[mt][nt][r];
    }
    ssum += __shfl_xor(ssum, 16, 64);
    ssum += __shfl_xor(ssum, 32, 64);
    x4[nt] = 2.f * feats[(size_t)n * 64 + nt * 16 + c15] + ssum;
  }

  float sum = x4[0] + x4[1] + x4[2] + x4[3];
  float sum2 = x4[0] * x4[0] + x4[1] * x4[1] + x4[2] * x4[2] + x4[3] * x4[3];
#pragma unroll
  for (int m = 1; m < 16; m <<= 1) {
    sum += __shfl_xor(sum, m, 64);
    sum2 += __shfl_xor(sum2, m, 64);
  }
  float mean = sum * (1.f / 64.f);
  float var = sum2 * (1.f / 64.f) - mean * mean;
  float inv = rsqrtf(var + EPSF);
  h_out[(size_t)n * 64 + lane] =
      (_Float16)(g_att[lane] * (x4[g] - mean) * inv + b_att[lane]);
}

// ---------------------------------------------------------------------------
// Kernel B v4: graph conv + FFN + LN. Block = 16 points.
// Phase 1: SCALAR-indexed gather — wave id forced uniform via readfirstlane,
// so neighbor ids come from s_load and each h-row read is one saddr-form
// 128B global load (no shfl, no per-lane address math).
// Phase 2 (wave 0): MFMA GEMMs + coords term + residual + LN + store.
// ---------------------------------------------------------------------------
__global__ __launch_bounds__(256) void gconv_kernel(
    const float* __restrict__ coords, const _Float16* __restrict__ h,
    const _Float16* __restrict__ wtg, const float* __restrict__ Wsg,
    const float* __restrict__ bsg, const float* __restrict__ bf,
    const float* __restrict__ g_ff, const float* __restrict__ b_ff,
    const int* __restrict__ knn, float* __restrict__ out)
{
  __shared__ float agg_s[16 * 68];      // padded rows: <=2-way banks
  __shared__ float cm_s[16 * 4];
  __shared__ float T2[2048];
  const int wv = __builtin_amdgcn_readfirstlane(threadIdx.x >> 6);
  const int lane = threadIdx.x & 63;
  const int c15 = lane & 15, g = lane >> 4;
  const int n0 = blockIdx.x * 16;
  const float inv33 = 1.0f / 33.0f;
  const _Float16* wt_sg = wtg + 5 * 4096;
  const _Float16* wt_f  = wtg + 6 * 4096;

  // ---- phase 1: gather, 4 points per wave, all-scalar indices ----
#pragma unroll
  for (int i = 0; i < 4; ++i) {
    int pl = wv * 4 + i;
    int p = n0 + pl;                               // wave-uniform
    const int* row = knn + (size_t)p * 33;         // uniform ptr -> s_load
    float acc = (float)h[(size_t)p * 64 + lane];   // self loop
#pragma unroll 8
    for (int k = 1; k <= 32; ++k) {
      int idx = __builtin_amdgcn_readfirstlane(row[k]);
      acc += (float)h[(size_t)idx * 64 + lane];    // saddr 128B coalesced row
    }
    agg_s[pl * 68 + lane] = acc * inv33;

    // coords aggregate: lanes 0..32, butterfly-reduce
    float sx = 0.f, sy = 0.f, sz = 0.f;
    if (lane < 33) {
      int src = (lane == 0) ? p : row[lane];
      sx = coords[(size_t)src * 3];
      sy = coords[(size_t)src * 3 + 1];
      sz = coords[(size_t)src * 3 + 2];
    }
#pragma unroll
    for (int m = 1; m < 64; m <<= 1) {
      sx += __shfl_xor(sx, m, 64);
      sy += __shfl_xor(sy, m, 64);
      sz += __shfl_xor(sz, m, 64);
    }
    if (lane == 0) {
      cm_s[pl * 4 + 0] = sx * inv33;
      cm_s[pl * 4 + 1] = sy * inv33;
      cm_s[pl * 4 + 2] = sz * inv33;
    }
  }
  __syncthreads();
  if (wv != 0) return;

  // ---- phase 2 (wave 0): A-frags from agg tile (row m = point c15) ----
  half8 aA[2];
#pragma unroll
  for (int ks = 0; ks < 2; ++ks) {
    const float* pr = agg_s + c15 * 68 + ks * 32 + g * 8;
    float4 u0 = *(const float4*)pr, u1 = *(const float4*)(pr + 4);
    aA[ks][0] = (_Float16)u0.x; aA[ks][1] = (_Float16)u0.y;
    aA[ks][2] = (_Float16)u0.z; aA[ks][3] = (_Float16)u0.w;
    aA[ks][4] = (_Float16)u1.x; aA[ks][5] = (_Float16)u1.y;
    aA[ks][6] = (_Float16)u1.z; aA[ks][7] = (_Float16)u1.w;
  }

  float cmx[4], cmy[4], cmz[4];
#pragma unroll
  for (int r = 0; r < 4; ++r) {
    int pl = g * 4 + r;
    cmx[r] = cm_s[pl * 4 + 0];
    cmy[r] = cm_s[pl * 4 + 1];
    cmz[r] = cm_s[pl * 4 + 2];
  }

  // ---- t1 = relu(agg @ Wsg + coords-part + bsg) -> T2 ----
  {
    floatx4 C1[4] = {};
    domm1(wt_sg, aA, c15, g, C1);
#pragma unroll
    for (int nt = 0; nt < 4; ++nt) {
      int col = nt * 16 + c15;
      float b = bsg[col];
      float w64 = Wsg[4096 + col], w65 = Wsg[4160 + col], w66 = Wsg[4224 + col];
      floatx4 v;
#pragma unroll
      for (int r = 0; r < 4; ++r)
        v[r] = fmaxf(C1[nt][r] + b + cmx[r] * w64 + cmy[r] * w65 + cmz[r] * w66, 0.f);
      stC(T2, c15, g, 0, nt, v);
    }
  }
  __builtin_amdgcn_wave_barrier();
  half8 aT[2];
  aT[0] = ldA(T2, c15, g, 0, 0);
  aT[1] = ldA(T2, c15, g, 0, 1);

  // ---- x = t1 @ Wf + bf + h_self; LN over d; store ----
  floatx4 C2[4] = {};
  domm1(wt_f, aT, c15, g, C2);
#pragma unroll
  for (int nt = 0; nt < 4; ++nt) {
    int col = nt * 16 + c15;
    float b = bf[col];
#pragma unroll
    for (int r = 0; r < 4; ++r)
      C2[nt][r] += b + (float)h[(size_t)(n0 + g * 4 + r) * 64 + col];
  }
#pragma unroll
  for (int r = 0; r < 4; ++r) {
    float s = C2[0][r] + C2[1][r] + C2[2][r] + C2[3][r];
    float s2 = C2[0][r] * C2[0][r] + C2[1][r] * C2[1][r] +
               C2[2][r] * C2[2][r] + C2[3][r] * C2[3][r];
#pragma unroll
    for (int m = 1; m < 16; m <<= 1) {
      s += __shfl_xor(s, m, 64);
      s2 += __shfl_xor(s2, m, 64);
    }
    float mean = s * (1.f / 64.f);
    float var = s2 * (1.f / 64.f) - mean * mean;
    float inv = rsqrtf(var + EPSF);
    int prow = n0 + g * 4 + r;
#pragma unroll
    for (int nt = 0; nt < 4; ++nt) {
      int col = nt * 16 + c15;
      out[(size_t)prow * 64 + col] =
          g_ff[col] * (C2[nt][r] - mean) * inv + b_ff[col];
    }
  }
}

extern "C" void kernel_launch(void* const* d_in, const int* in_sizes, int n_in,
                              void* d_out, int out_size, void* d_ws, size_t ws_size,
                              hipStream_t stream) {
  (void)in_sizes; (void)n_in; (void)out_size; (void)ws_size;
  const float* coords = (const float*)d_in[0];
  const float* feats  = (const float*)d_in[1];
  const float* Wq  = (const float*)d_in[2];  const float* bq  = (const float*)d_in[3];
  const float* Wk  = (const float*)d_in[4];  const float* bk  = (const float*)d_in[5];
  const float* Wv  = (const float*)d_in[6];  const float* bv  = (const float*)d_in[7];
  const float* Wl1 = (const float*)d_in[8];  const float* bl1 = (const float*)d_in[9];
  const float* Wl2 = (const float*)d_in[10]; const float* bl2 = (const float*)d_in[11];
  const float* Ww1 = (const float*)d_in[12]; const float* bw1 = (const float*)d_in[13];
  const float* Ww2 = (const float*)d_in[14]; const float* bw2 = (const float*)d_in[15];
  const float* g_att = (const float*)d_in[16]; const float* b_att = (const float*)d_in[17];
  const float* Wsg = (const float*)d_in[18]; const float* bsg = (const float*)d_in[19];
  const float* Wf  = (const float*)d_in[20]; const float* bf  = (const float*)d_in[21];
  const float* g_ff = (const float*)d_in[22]; const float* b_ff = (const float*)d_in[23];
  const int* knn = (const int*)d_in[24];

  // ws: [0, 2.56MB) h fp16 | [2.56MB, +56KB) swizzled weights | Qh fp16
  _Float16* h   = (_Float16*)d_ws;
  _Float16* wtg = (_Float16*)((char*)d_ws + 2621440);
  _Float16* Qh  = (_Float16*)((char*)d_ws + 2621440 + 57344);
  float* out = (float*)d_out;

  prep_q_kernel<<<dim3(164), dim3(256), 0, stream>>>(
      Wl2, Wv, Wk, Ww1, Ww2, Wsg, Wf, Wq, feats, bq, wtg, Qh);
  attn_kernel<<<dim3(NPTS / 4), dim3(256), 0, stream>>>(
      coords, feats, bk, bv, Wl1, bl1, bl2, bw1, bw2,
      g_att, b_att, knn, wtg, Qh, h);
  gconv_kernel<<<dim3(NPTS / 16), dim3(256), 0, stream>>>(
      coords, h, wtg, Wsg, bsg, bf, g_ff, b_ff, knn, out);
}